// Round 3
// baseline (1282.061 us; speedup 1.0000x reference)
//
#include <hip/hip_runtime.h>
#include <float.h>

#define B_N 16384
#define G_N 8192
#define D_N 1024
#define NKT 48   // virtual K = 3072 = 48 K-tiles of 64

typedef unsigned short u16;
typedef unsigned long long u64;
typedef __attribute__((ext_vector_type(8))) short short8;
typedef __attribute__((ext_vector_type(4))) float f32x4;

#define AS1 __attribute__((address_space(1)))
#define AS3 __attribute__((address_space(3)))

// ======================= common small kernels =======================

__global__ __launch_bounds__(256) void k_norms(const float* __restrict__ g,
                                               float* __restrict__ invn) {
    const int j = blockIdx.x;
    const int t = threadIdx.x;
    const float4 v = *reinterpret_cast<const float4*>(&g[(size_t)j * D_N + t * 4]);
    float s = v.x * v.x + v.y * v.y + v.z * v.z + v.w * v.w;
#pragma unroll
    for (int off = 32; off >= 1; off >>= 1) s += __shfl_down(s, off, 64);
    __shared__ float wsum[4];
    if ((t & 63) == 0) wsum[t >> 6] = s;
    __syncthreads();
    if (t == 0) {
        const float tot = wsum[0] + wsum[1] + wsum[2] + wsum[3];
        invn[j] = 1.0f / fmaxf(sqrtf(tot), 1e-12f);
    }
}

__global__ void k_counts(const u64* __restrict__ pk, int* __restrict__ counts) {
    const int i = blockIdx.x * blockDim.x + threadIdx.x;
    if (i < B_N) {
        const int a = 8191 - (int)(pk[i] & 0x1FFFull);
        atomicAdd(&counts[a], 1);
    }
}

__global__ __launch_bounds__(256) void k_scatter(const float* __restrict__ x,
                                                 const u64* __restrict__ pk,
                                                 const int* __restrict__ counts,
                                                 float* __restrict__ contrib) {
    const int i = blockIdx.x;
    const int a = 8191 - (int)(pk[i] & 0x1FFFull);
    const float scale = 1.0f / (float)counts[a];
    const int t = threadIdx.x;
    const float4 v = *reinterpret_cast<const float4*>(&x[(size_t)i * D_N + t * 4]);
    float* dst = &contrib[(size_t)a * D_N + t * 4];
    atomicAdd(dst + 0, v.x * scale);
    atomicAdd(dst + 1, v.y * scale);
    atomicAdd(dst + 2, v.z * scale);
    atomicAdd(dst + 3, v.w * scale);
}

__global__ __launch_bounds__(256) void k_finalize(const float* __restrict__ g,
                                                  const int* __restrict__ counts,
                                                  float* __restrict__ out) {
    const int j = blockIdx.x;
    const int t = threadIdx.x;
    const float sc = (counts[j] > 0) ? 0.99f : 1.0f;
    const float4 gv = *reinterpret_cast<const float4*>(&g[(size_t)j * D_N + t * 4]);
    const float4 cv = *reinterpret_cast<const float4*>(&out[(size_t)j * D_N + t * 4]);
    float4 gf;
    gf.x = sc * gv.x + 0.01f * cv.x;
    gf.y = sc * gv.y + 0.01f * cv.y;
    gf.z = sc * gv.z + 0.01f * cv.z;
    gf.w = sc * gv.w + 0.01f * cv.w;
    float s = gf.x * gf.x + gf.y * gf.y + gf.z * gf.z + gf.w * gf.w;
#pragma unroll
    for (int off = 32; off >= 1; off >>= 1) s += __shfl_down(s, off, 64);
    __shared__ float wsum[4];
    __shared__ float s_inv;
    if ((t & 63) == 0) wsum[t >> 6] = s;
    __syncthreads();
    if (t == 0) s_inv = 1.0f / fmaxf(sqrtf(wsum[0] + wsum[1] + wsum[2] + wsum[3]), 1e-12f);
    __syncthreads();
    gf.x *= s_inv; gf.y *= s_inv; gf.z *= s_inv; gf.w *= s_inv;
    *reinterpret_cast<float4*>(&out[(size_t)j * D_N + t * 4]) = gf;
}

// ======================= bf16 split prep =======================

__device__ inline u16 f2bf_rtn(float f) {
    unsigned u = __float_as_uint(f);
    unsigned r = u + 0x7fffu + ((u >> 16) & 1u);
    return (u16)(r >> 16);
}
__device__ inline float bf2f(u16 h) { return __uint_as_float(((unsigned)h) << 16); }

__global__ __launch_bounds__(256) void k_split(const float* __restrict__ src,
                                               u16* __restrict__ hi,
                                               u16* __restrict__ lo) {
    const size_t i4 = (size_t)blockIdx.x * 256 + threadIdx.x;
    const float4 v = *reinterpret_cast<const float4*>(&src[i4 * 4]);
    u16 h[4], l[4];
    const float f[4] = {v.x, v.y, v.z, v.w};
#pragma unroll
    for (int j = 0; j < 4; ++j) {
        h[j] = f2bf_rtn(f[j]);
        l[j] = f2bf_rtn(f[j] - bf2f(h[j]));
    }
    *reinterpret_cast<ushort4*>(&hi[i4 * 4]) = make_ushort4(h[0], h[1], h[2], h[3]);
    *reinterpret_cast<ushort4*>(&lo[i4 * 4]) = make_ushort4(l[0], l[1], l[2], l[3]);
}

// ======================= 8-phase 256x256 MFMA GEMM + fused argmax =======================
// Virtual K=3072: kt 0-15 -> x_hi.g_hi ; 16-31 -> x_lo.g_hi ; 32-47 -> x_hi.g_lo.
// 512 threads = 8 waves (2M x 4N); per-wave 128x64 C; BK=64.
// LDS 128KiB: buf[2] x {A: 2048 chunks, B: 2048 chunks}, fragment-major
// (chunk = mfrag16*128 + ks8*16 + rowin; frag read = contiguous 1KiB/wave, conflict-free).

__device__ __forceinline__ void stage_half(const u16* __restrict__ base, int r0, int ko,
                                           u16* dst_region, int tid) {
#pragma unroll
    for (int i = 0; i < 2; ++i) {
        const int c = tid + i * 512;                 // chunk id within half (0..1023)
        const int mf = c >> 7, ks8 = (c >> 4) & 7, ri = c & 15;
        const u16* src = base + (size_t)(r0 + mf * 16 + ri) * D_N + ko + ks8 * 8;
        u16* dst = dst_region + (size_t)((tid & 448) + i * 512) * 8;  // wave-uniform base
        __builtin_amdgcn_global_load_lds((const AS1 void*)src, (AS3 void*)dst, 16, 0, 0);
    }
}

#define PHASE(BUFI, Q, READB, STG, DOVM) do {                                              \
    const u16* aL = lds + (BUFI) * 32768;                                                  \
    const u16* bL = aL + 16384;                                                            \
    _Pragma("unroll")                                                                      \
    for (int dm = 0; dm < 2; ++dm)                                                         \
        _Pragma("unroll")                                                                  \
        for (int s = 0; s < 2; ++s)                                                        \
            afr[dm][s] = *reinterpret_cast<const short8*>(                                 \
                aL + (size_t)(((wr * 8 + (Q) * 2 + dm) * 128 + s * 64 + lane)) * 8);       \
    if (READB) {                                                                           \
        _Pragma("unroll")                                                                  \
        for (int n = 0; n < 4; ++n)                                                        \
            _Pragma("unroll")                                                              \
            for (int s = 0; s < 2; ++s)                                                    \
                bfr[n][s] = *reinterpret_cast<const short8*>(                              \
                    bL + (size_t)(((wc * 4 + n) * 128 + s * 64 + lane)) * 8);              \
    }                                                                                      \
    STG;                                                                                   \
    if (DOVM) asm volatile("s_waitcnt vmcnt(6)" ::: "memory");                             \
    __builtin_amdgcn_s_barrier();                                                          \
    asm volatile("s_waitcnt lgkmcnt(0)" ::: "memory");                                     \
    __builtin_amdgcn_sched_barrier(0);                                                     \
    __builtin_amdgcn_s_setprio(1);                                                         \
    _Pragma("unroll")                                                                      \
    for (int s = 0; s < 2; ++s)                                                            \
        _Pragma("unroll")                                                                  \
        for (int dm = 0; dm < 2; ++dm)                                                     \
            _Pragma("unroll")                                                              \
            for (int n = 0; n < 4; ++n)                                                    \
                acc[(Q) * 2 + dm][n] = __builtin_amdgcn_mfma_f32_16x16x32_bf16(            \
                    afr[dm][s], bfr[n][s], acc[(Q) * 2 + dm][n], 0, 0, 0);                 \
    __builtin_amdgcn_s_setprio(0);                                                         \
    __builtin_amdgcn_s_barrier();                                                          \
} while (0)

__global__ __launch_bounds__(512, 2) void k_gemm_argmax(
    const u16* __restrict__ x_hi, const u16* __restrict__ x_lo,
    const u16* __restrict__ g_hi, const u16* __restrict__ g_lo,
    const float* __restrict__ invn, u64* __restrict__ pk) {

    __shared__ __align__(16) u16 lds[65536];   // 128 KiB: 2 bufs x (A 32KB + B 32KB)

    const int bid = blockIdx.x;                // 2048 blocks
    const int xcd = bid & 7, lcl = bid >> 3;   // XCD-contiguous chunks
    const int mblk = xcd * 8 + (lcl >> 5);     // 0..63
    const int nblk = lcl & 31;                 // 0..31

    const int tid = threadIdx.x;
    const int lane = tid & 63;
    const int w = tid >> 6;
    const int wr = w >> 2, wc = w & 3;         // 2x4 wave grid
    const int mrow0 = mblk * 256;
    const int nrow0 = nblk * 256;

    auto STGA = [&](int ktx, int half) {
        int kt = ktx < NKT ? ktx : NKT - 1;    // clamp: identical-byte rewrite, ledger stays exact
        const u16* base = (kt >= 16 && kt < 32) ? x_lo : x_hi;
        stage_half(base, mrow0 + half * 128, (kt & 15) * 64,
                   lds + (kt & 1) * 32768 + half * 8192, tid);
    };
    auto STGB = [&](int ktx, int half) {
        int kt = ktx < NKT ? ktx : NKT - 1;
        const u16* base = (kt < 32) ? g_hi : g_lo;
        stage_half(base, nrow0 + half * 128, (kt & 15) * 64,
                   lds + (kt & 1) * 32768 + 16384 + half * 8192, tid);
    };

    f32x4 acc[8][4];
#pragma unroll
    for (int m = 0; m < 8; ++m)
#pragma unroll
        for (int n = 0; n < 4; ++n) acc[m][n] = (f32x4){0.f, 0.f, 0.f, 0.f};
    short8 afr[2][2], bfr[4][2];

    // prologue: K0 fully + K1 {B0,B1,A0}; vmcnt(6) => K0's 8 loads landed
    STGB(0, 0); STGB(0, 1); STGA(0, 0); STGA(0, 1);
    STGB(1, 0); STGB(1, 1); STGA(1, 0);
    asm volatile("s_waitcnt vmcnt(6)" ::: "memory");
    __builtin_amdgcn_s_barrier();

    for (int kt0 = 0; kt0 < NKT; kt0 += 2) {
        const int kt1 = kt0 + 1;
        PHASE(0, 0, true,  STGA(kt1, 1),     false);   // completes K-tile kt1's staging
        PHASE(0, 1, false, STGB(kt0 + 2, 0), false);
        PHASE(0, 2, false, STGB(kt0 + 2, 1), false);
        PHASE(0, 3, false, STGA(kt0 + 2, 0), true);    // vmcnt(6): kt1 fully landed
        PHASE(1, 0, true,  STGA(kt0 + 2, 1), false);
        PHASE(1, 1, false, STGB(kt1 + 2, 0), false);
        PHASE(1, 2, false, STGB(kt1 + 2, 1), false);
        PHASE(1, 3, false, STGA(kt1 + 2, 0), true);    // vmcnt(6): kt0+2 fully landed
    }

    // ---------- epilogue: invn-scale + packed argmax -> atomicMax ----------
    const int rl = lane & 15, kg = lane >> 4;
    float inv[4];
#pragma unroll
    for (int n = 0; n < 4; ++n) inv[n] = invn[nrow0 + wc * 64 + n * 16 + rl];

#pragma unroll
    for (int m = 0; m < 8; ++m) {
#pragma unroll
        for (int j = 0; j < 4; ++j) {
            u64 p = 0;
#pragma unroll
            for (int n = 0; n < 4; ++n) {
                const float v = acc[m][n][j] * inv[n];
                unsigned u = __float_as_uint(v);
                u ^= (u >> 31) ? 0xFFFFFFFFu : 0x80000000u;   // monotone float->uint
                const int col = nrow0 + wc * 64 + n * 16 + rl;
                const u64 cand = ((u64)u << 13) | (unsigned)(8191 - col);  // ties -> smaller col
                p = (cand > p) ? cand : p;
            }
#pragma unroll
            for (int msk = 1; msk < 16; msk <<= 1) {
                const u64 o = __shfl_xor(p, msk, 64);
                p = (o > p) ? o : p;
            }
            if (rl == 0) {
                const int row = mrow0 + wr * 128 + m * 16 + kg * 4 + j;
                atomicMax(&pk[row], p);
            }
        }
    }
}

// ======================= fallback fp32 argmax (tiny-ws path) =======================

__global__ __launch_bounds__(256) void k_argmax_fp32(const float* __restrict__ x,
                                                     const float* __restrict__ g,
                                                     const float* __restrict__ invn,
                                                     int* __restrict__ assign) {
    __shared__ __align__(16) float As[32][68];
    __shared__ __align__(16) float Bs[32][68];
    const int t = threadIdx.x;
    const int tx = t & 15;
    const int ty = t >> 4;
    const int row0 = blockIdx.x * 64;
    const int r_a = t >> 3;
    const int c4 = t & 7;
    float bestv[4]; int besti[4];
#pragma unroll
    for (int i = 0; i < 4; ++i) { bestv[i] = -3.0e38f; besti[i] = 0; }
    for (int jt = 0; jt < G_N / 64; ++jt) {
        float acc[4][4] = {};
        for (int kt = 0; kt < D_N / 32; ++kt) {
#pragma unroll
            for (int p = 0; p < 2; ++p) {
                const int r = r_a + p * 32;
                const float4 va = *reinterpret_cast<const float4*>(&x[(size_t)(row0 + r) * D_N + kt * 32 + c4 * 4]);
                As[c4 * 4 + 0][r] = va.x; As[c4 * 4 + 1][r] = va.y; As[c4 * 4 + 2][r] = va.z; As[c4 * 4 + 3][r] = va.w;
                const float4 vb = *reinterpret_cast<const float4*>(&g[(size_t)(jt * 64 + r) * D_N + kt * 32 + c4 * 4]);
                Bs[c4 * 4 + 0][r] = vb.x; Bs[c4 * 4 + 1][r] = vb.y; Bs[c4 * 4 + 2][r] = vb.z; Bs[c4 * 4 + 3][r] = vb.w;
            }
            __syncthreads();
#pragma unroll
            for (int k = 0; k < 32; ++k) {
                const float4 a = *reinterpret_cast<const float4*>(&As[k][ty * 4]);
                const float4 b = *reinterpret_cast<const float4*>(&Bs[k][tx * 4]);
                const float av[4] = {a.x, a.y, a.z, a.w};
                const float bv[4] = {b.x, b.y, b.z, b.w};
#pragma unroll
                for (int i = 0; i < 4; ++i)
#pragma unroll
                    for (int jj = 0; jj < 4; ++jj) acc[i][jj] += av[i] * bv[jj];
            }
            __syncthreads();
        }
#pragma unroll
        for (int jj = 0; jj < 4; ++jj) {
            const int col = jt * 64 + tx * 4 + jj;
            const float s = invn[col];
#pragma unroll
            for (int i = 0; i < 4; ++i) {
                const float v = acc[i][jj] * s;
                if (v > bestv[i]) { bestv[i] = v; besti[i] = col; }
            }
        }
    }
#pragma unroll
    for (int m = 1; m < 16; m <<= 1) {
#pragma unroll
        for (int i = 0; i < 4; ++i) {
            const float ov = __shfl_xor(bestv[i], m, 64);
            const int oi = __shfl_xor(besti[i], m, 64);
            if (ov > bestv[i] || (ov == bestv[i] && oi < besti[i])) { bestv[i] = ov; besti[i] = oi; }
        }
    }
    if (tx == 0) {
#pragma unroll
        for (int i = 0; i < 4; ++i) assign[row0 + ty * 4 + i] = besti[i];
    }
}

__global__ void k_counts_i(const int* __restrict__ assign, int* __restrict__ counts) {
    const int i = blockIdx.x * blockDim.x + threadIdx.x;
    if (i < B_N) atomicAdd(&counts[assign[i]], 1);
}

__global__ __launch_bounds__(256) void k_scatter_i(const float* __restrict__ x,
                                                   const int* __restrict__ assign,
                                                   const int* __restrict__ counts,
                                                   float* __restrict__ contrib) {
    const int i = blockIdx.x;
    const int a = assign[i];
    const float scale = 1.0f / (float)counts[a];
    const int t = threadIdx.x;
    const float4 v = *reinterpret_cast<const float4*>(&x[(size_t)i * D_N + t * 4]);
    float* dst = &contrib[(size_t)a * D_N + t * 4];
    atomicAdd(dst + 0, v.x * scale);
    atomicAdd(dst + 1, v.y * scale);
    atomicAdd(dst + 2, v.z * scale);
    atomicAdd(dst + 3, v.w * scale);
}

// ======================= launch =======================

extern "C" void kernel_launch(void* const* d_in, const int* in_sizes, int n_in,
                              void* d_out, int out_size, void* d_ws, size_t ws_size,
                              hipStream_t stream) {
    const float* x = (const float*)d_in[0];   // [16384, 1024]
    const float* g = (const float*)d_in[1];   // [8192, 1024]
    float* out = (float*)d_out;               // [8192, 1024]; doubles as contrib accumulator

    char* ws = (char*)d_ws;
    u16*  x_hi  = (u16*)(ws);                     // 32 MiB
    u16*  x_lo  = (u16*)(ws + 33554432);          // 32 MiB
    u16*  g_hi  = (u16*)(ws + 67108864);          // 16 MiB
    u16*  g_lo  = (u16*)(ws + 83886080);          // 16 MiB
    float* invn = (float*)(ws + 100663296);       // 32 KiB
    int* counts = (int*)(ws + 100696064);         // 32 KiB
    u64*   pk   = (u64*)(ws + 100728832);         // 128 KiB packed (value|col) per row
    const size_t need = 100859904;

    hipMemsetAsync(out, 0, (size_t)G_N * D_N * sizeof(float), stream);

    if (ws_size >= need) {
        hipMemsetAsync(counts, 0, (size_t)G_N * sizeof(int), stream);
        hipMemsetAsync(pk, 0, (size_t)B_N * sizeof(u64), stream);
        k_norms<<<G_N, 256, 0, stream>>>(g, invn);
        k_split<<<B_N * D_N / 4 / 256, 256, 0, stream>>>(x, x_hi, x_lo);
        k_split<<<G_N * D_N / 4 / 256, 256, 0, stream>>>(g, g_hi, g_lo);
        k_gemm_argmax<<<2048, 512, 0, stream>>>(x_hi, x_lo, g_hi, g_lo, invn, pk);
        k_counts<<<B_N / 256, 256, 0, stream>>>(pk, counts);
        k_scatter<<<B_N, 256, 0, stream>>>(x, pk, counts, out);
        k_finalize<<<G_N, 256, 0, stream>>>(g, counts, out);
    } else {
        // fallback: fp32 vector path (128 KiB scratch)
        float* invn_f = (float*)ws;
        int* assign_f = (int*)(ws + (size_t)G_N * 4);
        int* counts_f = (int*)(ws + (size_t)(G_N + B_N) * 4);
        hipMemsetAsync(counts_f, 0, (size_t)G_N * sizeof(int), stream);
        k_norms<<<G_N, 256, 0, stream>>>(g, invn_f);
        k_argmax_fp32<<<B_N / 64, 256, 0, stream>>>(x, g, invn_f, assign_f);
        k_counts_i<<<B_N / 256, 256, 0, stream>>>(assign_f, counts_f);
        k_scatter_i<<<B_N, 256, 0, stream>>>(x, assign_f, counts_f, out);
        k_finalize<<<G_N, 256, 0, stream>>>(g, counts_f, out);
    }
}

// Round 4
// 1166.257 us; speedup vs baseline: 1.0993x; 1.0993x over previous
//
#include <hip/hip_runtime.h>
#include <float.h>

#define B_N 16384
#define G_N 8192
#define D_N 1024
#define NKT 48   // virtual K = 3072 = 48 K-tiles of 64

typedef unsigned short u16;
typedef unsigned long long u64;
typedef __attribute__((ext_vector_type(8))) short short8;
typedef __attribute__((ext_vector_type(4))) float f32x4;

#define AS1 __attribute__((address_space(1)))
#define AS3 __attribute__((address_space(3)))

// ======================= common small kernels =======================

__global__ __launch_bounds__(256) void k_norms(const float* __restrict__ g,
                                               float* __restrict__ invn) {
    const int j = blockIdx.x;
    const int t = threadIdx.x;
    const float4 v = *reinterpret_cast<const float4*>(&g[(size_t)j * D_N + t * 4]);
    float s = v.x * v.x + v.y * v.y + v.z * v.z + v.w * v.w;
#pragma unroll
    for (int off = 32; off >= 1; off >>= 1) s += __shfl_down(s, off, 64);
    __shared__ float wsum[4];
    if ((t & 63) == 0) wsum[t >> 6] = s;
    __syncthreads();
    if (t == 0) {
        const float tot = wsum[0] + wsum[1] + wsum[2] + wsum[3];
        invn[j] = 1.0f / fmaxf(sqrtf(tot), 1e-12f);
    }
}

__global__ void k_counts(const u64* __restrict__ pk, int* __restrict__ counts) {
    const int i = blockIdx.x * blockDim.x + threadIdx.x;
    if (i < B_N) {
        const int a = 8191 - (int)(pk[i] & 0x1FFFull);
        atomicAdd(&counts[a], 1);
    }
}

__global__ __launch_bounds__(256) void k_scatter(const float* __restrict__ x,
                                                 const u64* __restrict__ pk,
                                                 const int* __restrict__ counts,
                                                 float* __restrict__ contrib) {
    const int i = blockIdx.x;
    const int a = 8191 - (int)(pk[i] & 0x1FFFull);
    const float scale = 1.0f / (float)counts[a];
    const int t = threadIdx.x;
    const float4 v = *reinterpret_cast<const float4*>(&x[(size_t)i * D_N + t * 4]);
    float* dst = &contrib[(size_t)a * D_N + t * 4];
    atomicAdd(dst + 0, v.x * scale);
    atomicAdd(dst + 1, v.y * scale);
    atomicAdd(dst + 2, v.z * scale);
    atomicAdd(dst + 3, v.w * scale);
}

__global__ __launch_bounds__(256) void k_finalize(const float* __restrict__ g,
                                                  const int* __restrict__ counts,
                                                  float* __restrict__ out) {
    const int j = blockIdx.x;
    const int t = threadIdx.x;
    const float sc = (counts[j] > 0) ? 0.99f : 1.0f;
    const float4 gv = *reinterpret_cast<const float4*>(&g[(size_t)j * D_N + t * 4]);
    const float4 cv = *reinterpret_cast<const float4*>(&out[(size_t)j * D_N + t * 4]);
    float4 gf;
    gf.x = sc * gv.x + 0.01f * cv.x;
    gf.y = sc * gv.y + 0.01f * cv.y;
    gf.z = sc * gv.z + 0.01f * cv.z;
    gf.w = sc * gv.w + 0.01f * cv.w;
    float s = gf.x * gf.x + gf.y * gf.y + gf.z * gf.z + gf.w * gf.w;
#pragma unroll
    for (int off = 32; off >= 1; off >>= 1) s += __shfl_down(s, off, 64);
    __shared__ float wsum[4];
    __shared__ float s_inv;
    if ((t & 63) == 0) wsum[t >> 6] = s;
    __syncthreads();
    if (t == 0) s_inv = 1.0f / fmaxf(sqrtf(wsum[0] + wsum[1] + wsum[2] + wsum[3]), 1e-12f);
    __syncthreads();
    gf.x *= s_inv; gf.y *= s_inv; gf.z *= s_inv; gf.w *= s_inv;
    *reinterpret_cast<float4*>(&out[(size_t)j * D_N + t * 4]) = gf;
}

// ======================= bf16 split prep =======================

__device__ inline u16 f2bf_rtn(float f) {
    unsigned u = __float_as_uint(f);
    unsigned r = u + 0x7fffu + ((u >> 16) & 1u);
    return (u16)(r >> 16);
}
__device__ inline float bf2f(u16 h) { return __uint_as_float(((unsigned)h) << 16); }

__global__ __launch_bounds__(256) void k_split(const float* __restrict__ src,
                                               u16* __restrict__ hi,
                                               u16* __restrict__ lo) {
    const size_t i4 = (size_t)blockIdx.x * 256 + threadIdx.x;
    const float4 v = *reinterpret_cast<const float4*>(&src[i4 * 4]);
    u16 h[4], l[4];
    const float f[4] = {v.x, v.y, v.z, v.w};
#pragma unroll
    for (int j = 0; j < 4; ++j) {
        h[j] = f2bf_rtn(f[j]);
        l[j] = f2bf_rtn(f[j] - bf2f(h[j]));
    }
    *reinterpret_cast<ushort4*>(&hi[i4 * 4]) = make_ushort4(h[0], h[1], h[2], h[3]);
    *reinterpret_cast<ushort4*>(&lo[i4 * 4]) = make_ushort4(l[0], l[1], l[2], l[3]);
}

// ======================= 8-phase 256x256 MFMA GEMM + fused argmax =======================
// Virtual K=3072: kt 0-15 -> x_hi.g_hi ; 16-31 -> x_lo.g_hi ; 32-47 -> x_hi.g_lo.
// 512 threads = 8 waves (2M x 4N); per-wave 128x64 C; BK=64.
// LDS 128KiB: buf[2] x {A 32KB, B 32KB}; each region = 2 halves x [128 rows][64 bf16],
// XOR-swizzled: phys 16B-slot = logical_slot ^ (row & 7).
//   stage:  chunk p (0..1023/half): row=p>>3 (8 lanes/row -> coalesced 128B/row),
//           source col pre-permuted by inverse XOR; LDS dest linear (rule #21).
//   read:   frag(mf,s) @ mf*1024 + rl*64 + (((s*4+kg)^(rl&7))<<3) -> 2 lanes/slot = free.

#define PHASE(BUFI, Q, READB, STG, DOVM) do {                                              \
    const u16* aL = lds + (BUFI) * 32768;                                                  \
    const u16* bL = aL + 16384;                                                            \
    _Pragma("unroll")                                                                      \
    for (int dm = 0; dm < 2; ++dm) {                                                       \
        const u16* fb = aL + (wr * 8 + (Q) * 2 + dm) * 1024;                               \
        afr[dm][0] = *reinterpret_cast<const short8*>(fb + aoff0);                         \
        afr[dm][1] = *reinterpret_cast<const short8*>(fb + aoff1);                         \
    }                                                                                      \
    if (READB) {                                                                           \
        _Pragma("unroll")                                                                  \
        for (int n = 0; n < 4; ++n) {                                                      \
            const u16* fb = bL + (wc * 4 + n) * 1024;                                      \
            bfr[n][0] = *reinterpret_cast<const short8*>(fb + aoff0);                      \
            bfr[n][1] = *reinterpret_cast<const short8*>(fb + aoff1);                      \
        }                                                                                  \
    }                                                                                      \
    STG;                                                                                   \
    if (DOVM) asm volatile("s_waitcnt vmcnt(6)" ::: "memory");                             \
    __builtin_amdgcn_s_barrier();                                                          \
    asm volatile("s_waitcnt lgkmcnt(0)" ::: "memory");                                     \
    __builtin_amdgcn_s_setprio(1);                                                         \
    _Pragma("unroll")                                                                      \
    for (int s = 0; s < 2; ++s)                                                            \
        _Pragma("unroll")                                                                  \
        for (int dm = 0; dm < 2; ++dm)                                                     \
            _Pragma("unroll")                                                              \
            for (int n = 0; n < 4; ++n)                                                    \
                acc[(Q) * 2 + dm][n] = __builtin_amdgcn_mfma_f32_16x16x32_bf16(            \
                    afr[dm][s], bfr[n][s], acc[(Q) * 2 + dm][n], 0, 0, 0);                 \
    __builtin_amdgcn_s_setprio(0);                                                         \
    __builtin_amdgcn_s_barrier();                                                          \
} while (0)

__global__ __launch_bounds__(512, 2) void k_gemm_argmax(
    const u16* __restrict__ x_hi, const u16* __restrict__ x_lo,
    const u16* __restrict__ g_hi, const u16* __restrict__ g_lo,
    const float* __restrict__ invn, u64* __restrict__ pk) {

    __shared__ __align__(16) u16 lds[65536];   // 128 KiB

    const int bid = blockIdx.x;                // 2048 blocks
    const int xcd = bid & 7, lcl = bid >> 3;
    const int mblk = xcd * 8 + (lcl >> 5);     // 0..63
    const int nblk = lcl & 31;                 // 0..31

    const int tid = threadIdx.x;
    const int lane = tid & 63;
    const int w = tid >> 6;
    const int wr = w >> 2, wc = w & 3;         // 2x4 wave grid
    const int mrow0 = mblk * 256;
    const int nrow0 = nblk * 256;

    // fragment-read lane constants
    const int rl = lane & 15, kg = lane >> 4;
    const int xr = rl & 7;
    const int sl0 = kg ^ xr;                          // phys slot, s=0
    const int aoff0 = rl * 64 + (sl0 << 3);           // u16 offset within frag
    const int aoff1 = rl * 64 + ((sl0 ^ 4) << 3);     // s=1

    // staging lane constants: chunk p0=tid (+512 for second load)
    const size_t soff0 = (size_t)(tid >> 3) * D_N + (size_t)(((tid & 7) ^ ((tid >> 3) & 7)) * 8);
    const size_t soff1 = soff0 + (size_t)64 * D_N;    // row += 64, slot xor unchanged
    const int wub = (tid & 448) * 8;                  // wave-uniform u16 base (chunk*8)

    auto STGA = [&](int ktx, int half) {
        int kt = ktx < NKT ? ktx : NKT - 1;    // clamp: identical-byte rewrite, ledger exact
        const u16* base = (kt >= 16 && kt < 32) ? x_lo : x_hi;
        const u16* s0 = base + (size_t)(mrow0 + half * 128) * D_N + (kt & 15) * 64;
        u16* dreg = lds + (kt & 1) * 32768 + half * 8192;
        __builtin_amdgcn_global_load_lds((const AS1 void*)(s0 + soff0), (AS3 void*)(dreg + wub), 16, 0, 0);
        __builtin_amdgcn_global_load_lds((const AS1 void*)(s0 + soff1), (AS3 void*)(dreg + wub + 4096), 16, 0, 0);
    };
    auto STGB = [&](int ktx, int half) {
        int kt = ktx < NKT ? ktx : NKT - 1;
        const u16* base = (kt < 32) ? g_hi : g_lo;
        const u16* s0 = base + (size_t)(nrow0 + half * 128) * D_N + (kt & 15) * 64;
        u16* dreg = lds + (kt & 1) * 32768 + 16384 + half * 8192;
        __builtin_amdgcn_global_load_lds((const AS1 void*)(s0 + soff0), (AS3 void*)(dreg + wub), 16, 0, 0);
        __builtin_amdgcn_global_load_lds((const AS1 void*)(s0 + soff1), (AS3 void*)(dreg + wub + 4096), 16, 0, 0);
    };

    f32x4 acc[8][4];
#pragma unroll
    for (int m = 0; m < 8; ++m)
#pragma unroll
        for (int n = 0; n < 4; ++n) acc[m][n] = (f32x4){0.f, 0.f, 0.f, 0.f};
    short8 afr[2][2], bfr[4][2];

    // prologue: K0 fully + K1 {B0,B1,A0}; vmcnt(6) => K0's 8 loads landed
    STGB(0, 0); STGB(0, 1); STGA(0, 0); STGA(0, 1);
    STGB(1, 0); STGB(1, 1); STGA(1, 0);
    asm volatile("s_waitcnt vmcnt(6)" ::: "memory");
    __builtin_amdgcn_s_barrier();

    for (int kt0 = 0; kt0 < NKT; kt0 += 2) {
        const int kt1 = kt0 + 1;
        PHASE(0, 0, true,  STGA(kt1, 1),     false);   // completes kt1's staging
        PHASE(0, 1, false, STGB(kt0 + 2, 0), false);
        PHASE(0, 2, false, STGB(kt0 + 2, 1), false);
        PHASE(0, 3, false, STGA(kt0 + 2, 0), true);    // vmcnt(6): kt1 fully landed
        PHASE(1, 0, true,  STGA(kt0 + 2, 1), false);
        PHASE(1, 1, false, STGB(kt1 + 2, 0), false);
        PHASE(1, 2, false, STGB(kt1 + 2, 1), false);
        PHASE(1, 3, false, STGA(kt1 + 2, 0), true);    // vmcnt(6): kt0+2 fully landed
    }

    // ---------- epilogue: invn-scale + packed argmax -> atomicMax ----------
    float inv[4];
#pragma unroll
    for (int n = 0; n < 4; ++n) inv[n] = invn[nrow0 + wc * 64 + n * 16 + rl];

#pragma unroll
    for (int m = 0; m < 8; ++m) {
#pragma unroll
        for (int j = 0; j < 4; ++j) {
            u64 p = 0;
#pragma unroll
            for (int n = 0; n < 4; ++n) {
                const float v = acc[m][n][j] * inv[n];
                unsigned u = __float_as_uint(v);
                u ^= (u >> 31) ? 0xFFFFFFFFu : 0x80000000u;   // monotone float->uint
                const int col = nrow0 + wc * 64 + n * 16 + rl;
                const u64 cand = ((u64)u << 13) | (unsigned)(8191 - col);  // ties -> smaller col
                p = (cand > p) ? cand : p;
            }
#pragma unroll
            for (int msk = 1; msk < 16; msk <<= 1) {
                const u64 o = __shfl_xor(p, msk, 64);
                p = (o > p) ? o : p;
            }
            if (rl == 0) {
                const int row = mrow0 + wr * 128 + m * 16 + kg * 4 + j;
                atomicMax(&pk[row], p);
            }
        }
    }
}

// ======================= fallback fp32 argmax (tiny-ws path) =======================

__global__ __launch_bounds__(256) void k_argmax_fp32(const float* __restrict__ x,
                                                     const float* __restrict__ g,
                                                     const float* __restrict__ invn,
                                                     int* __restrict__ assign) {
    __shared__ __align__(16) float As[32][68];
    __shared__ __align__(16) float Bs[32][68];
    const int t = threadIdx.x;
    const int tx = t & 15;
    const int ty = t >> 4;
    const int row0 = blockIdx.x * 64;
    const int r_a = t >> 3;
    const int c4 = t & 7;
    float bestv[4]; int besti[4];
#pragma unroll
    for (int i = 0; i < 4; ++i) { bestv[i] = -3.0e38f; besti[i] = 0; }
    for (int jt = 0; jt < G_N / 64; ++jt) {
        float acc[4][4] = {};
        for (int kt = 0; kt < D_N / 32; ++kt) {
#pragma unroll
            for (int p = 0; p < 2; ++p) {
                const int r = r_a + p * 32;
                const float4 va = *reinterpret_cast<const float4*>(&x[(size_t)(row0 + r) * D_N + kt * 32 + c4 * 4]);
                As[c4 * 4 + 0][r] = va.x; As[c4 * 4 + 1][r] = va.y; As[c4 * 4 + 2][r] = va.z; As[c4 * 4 + 3][r] = va.w;
                const float4 vb = *reinterpret_cast<const float4*>(&g[(size_t)(jt * 64 + r) * D_N + kt * 32 + c4 * 4]);
                Bs[c4 * 4 + 0][r] = vb.x; Bs[c4 * 4 + 1][r] = vb.y; Bs[c4 * 4 + 2][r] = vb.z; Bs[c4 * 4 + 3][r] = vb.w;
            }
            __syncthreads();
#pragma unroll
            for (int k = 0; k < 32; ++k) {
                const float4 a = *reinterpret_cast<const float4*>(&As[k][ty * 4]);
                const float4 b = *reinterpret_cast<const float4*>(&Bs[k][tx * 4]);
                const float av[4] = {a.x, a.y, a.z, a.w};
                const float bv[4] = {b.x, b.y, b.z, b.w};
#pragma unroll
                for (int i = 0; i < 4; ++i)
#pragma unroll
                    for (int jj = 0; jj < 4; ++jj) acc[i][jj] += av[i] * bv[jj];
            }
            __syncthreads();
        }
#pragma unroll
        for (int jj = 0; jj < 4; ++jj) {
            const int col = jt * 64 + tx * 4 + jj;
            const float s = invn[col];
#pragma unroll
            for (int i = 0; i < 4; ++i) {
                const float v = acc[i][jj] * s;
                if (v > bestv[i]) { bestv[i] = v; besti[i] = col; }
            }
        }
    }
#pragma unroll
    for (int m = 1; m < 16; m <<= 1) {
#pragma unroll
        for (int i = 0; i < 4; ++i) {
            const float ov = __shfl_xor(bestv[i], m, 64);
            const int oi = __shfl_xor(besti[i], m, 64);
            if (ov > bestv[i] || (ov == bestv[i] && oi < besti[i])) { bestv[i] = ov; besti[i] = oi; }
        }
    }
    if (tx == 0) {
#pragma unroll
        for (int i = 0; i < 4; ++i) assign[row0 + ty * 4 + i] = besti[i];
    }
}

__global__ void k_counts_i(const int* __restrict__ assign, int* __restrict__ counts) {
    const int i = blockIdx.x * blockDim.x + threadIdx.x;
    if (i < B_N) atomicAdd(&counts[assign[i]], 1);
}

__global__ __launch_bounds__(256) void k_scatter_i(const float* __restrict__ x,
                                                   const int* __restrict__ assign,
                                                   const int* __restrict__ counts,
                                                   float* __restrict__ contrib) {
    const int i = blockIdx.x;
    const int a = assign[i];
    const float scale = 1.0f / (float)counts[a];
    const int t = threadIdx.x;
    const float4 v = *reinterpret_cast<const float4*>(&x[(size_t)i * D_N + t * 4]);
    float* dst = &contrib[(size_t)a * D_N + t * 4];
    atomicAdd(dst + 0, v.x * scale);
    atomicAdd(dst + 1, v.y * scale);
    atomicAdd(dst + 2, v.z * scale);
    atomicAdd(dst + 3, v.w * scale);
}

// ======================= launch =======================

extern "C" void kernel_launch(void* const* d_in, const int* in_sizes, int n_in,
                              void* d_out, int out_size, void* d_ws, size_t ws_size,
                              hipStream_t stream) {
    const float* x = (const float*)d_in[0];   // [16384, 1024]
    const float* g = (const float*)d_in[1];   // [8192, 1024]
    float* out = (float*)d_out;               // [8192, 1024]; doubles as contrib accumulator

    char* ws = (char*)d_ws;
    u16*  x_hi  = (u16*)(ws);                     // 32 MiB
    u16*  x_lo  = (u16*)(ws + 33554432);          // 32 MiB
    u16*  g_hi  = (u16*)(ws + 67108864);          // 16 MiB
    u16*  g_lo  = (u16*)(ws + 83886080);          // 16 MiB
    float* invn = (float*)(ws + 100663296);       // 32 KiB
    int* counts = (int*)(ws + 100696064);         // 32 KiB
    u64*   pk   = (u64*)(ws + 100728832);         // 128 KiB packed (value|col) per row
    const size_t need = 100859904;

    hipMemsetAsync(out, 0, (size_t)G_N * D_N * sizeof(float), stream);

    if (ws_size >= need) {
        hipMemsetAsync(counts, 0, (size_t)G_N * sizeof(int), stream);
        hipMemsetAsync(pk, 0, (size_t)B_N * sizeof(u64), stream);
        k_norms<<<G_N, 256, 0, stream>>>(g, invn);
        k_split<<<B_N * D_N / 4 / 256, 256, 0, stream>>>(x, x_hi, x_lo);
        k_split<<<G_N * D_N / 4 / 256, 256, 0, stream>>>(g, g_hi, g_lo);
        k_gemm_argmax<<<2048, 512, 0, stream>>>(x_hi, x_lo, g_hi, g_lo, invn, pk);
        k_counts<<<B_N / 256, 256, 0, stream>>>(pk, counts);
        k_scatter<<<B_N, 256, 0, stream>>>(x, pk, counts, out);
        k_finalize<<<G_N, 256, 0, stream>>>(g, counts, out);
    } else {
        // fallback: fp32 vector path (128 KiB scratch)
        float* invn_f = (float*)ws;
        int* assign_f = (int*)(ws + (size_t)G_N * 4);
        int* counts_f = (int*)(ws + (size_t)(G_N + B_N) * 4);
        hipMemsetAsync(counts_f, 0, (size_t)G_N * sizeof(int), stream);
        k_norms<<<G_N, 256, 0, stream>>>(g, invn_f);
        k_argmax_fp32<<<B_N / 64, 256, 0, stream>>>(x, g, invn_f, assign_f);
        k_counts_i<<<B_N / 256, 256, 0, stream>>>(assign_f, counts_f);
        k_scatter_i<<<B_N, 256, 0, stream>>>(x, assign_f, counts_f, out);
        k_finalize<<<G_N, 256, 0, stream>>>(g, counts_f, out);
    }
}

// Round 5
// 1107.436 us; speedup vs baseline: 1.1577x; 1.0531x over previous
//
#include <hip/hip_runtime.h>
#include <float.h>

#define B_N 16384
#define G_N 8192
#define D_N 1024
#define NT 96   // virtual K = 3072 = 96 K-tiles of 32

typedef unsigned short u16;
typedef unsigned long long u64;
typedef __attribute__((ext_vector_type(8))) short short8;
typedef __attribute__((ext_vector_type(16))) float f32x16;

#define AS1 __attribute__((address_space(1)))
#define AS3 __attribute__((address_space(3)))

// ======================= common small kernels =======================

__global__ __launch_bounds__(256) void k_norms(const float* __restrict__ g,
                                               float* __restrict__ invn) {
    const int j = blockIdx.x;
    const int t = threadIdx.x;
    const float4 v = *reinterpret_cast<const float4*>(&g[(size_t)j * D_N + t * 4]);
    float s = v.x * v.x + v.y * v.y + v.z * v.z + v.w * v.w;
#pragma unroll
    for (int off = 32; off >= 1; off >>= 1) s += __shfl_down(s, off, 64);
    __shared__ float wsum[4];
    if ((t & 63) == 0) wsum[t >> 6] = s;
    __syncthreads();
    if (t == 0) {
        const float tot = wsum[0] + wsum[1] + wsum[2] + wsum[3];
        invn[j] = 1.0f / fmaxf(sqrtf(tot), 1e-12f);
    }
}

__global__ void k_counts(const u64* __restrict__ pk, int* __restrict__ counts) {
    const int i = blockIdx.x * blockDim.x + threadIdx.x;
    if (i < B_N) {
        const int a = 8191 - (int)(pk[i] & 0x1FFFull);
        atomicAdd(&counts[a], 1);
    }
}

__global__ __launch_bounds__(256) void k_scatter(const float* __restrict__ x,
                                                 const u64* __restrict__ pk,
                                                 const int* __restrict__ counts,
                                                 float* __restrict__ contrib) {
    const int i = blockIdx.x;
    const int a = 8191 - (int)(pk[i] & 0x1FFFull);
    const float scale = 1.0f / (float)counts[a];
    const int t = threadIdx.x;
    const float4 v = *reinterpret_cast<const float4*>(&x[(size_t)i * D_N + t * 4]);
    float* dst = &contrib[(size_t)a * D_N + t * 4];
    atomicAdd(dst + 0, v.x * scale);
    atomicAdd(dst + 1, v.y * scale);
    atomicAdd(dst + 2, v.z * scale);
    atomicAdd(dst + 3, v.w * scale);
}

__global__ __launch_bounds__(256) void k_finalize(const float* __restrict__ g,
                                                  const int* __restrict__ counts,
                                                  float* __restrict__ out) {
    const int j = blockIdx.x;
    const int t = threadIdx.x;
    const float sc = (counts[j] > 0) ? 0.99f : 1.0f;
    const float4 gv = *reinterpret_cast<const float4*>(&g[(size_t)j * D_N + t * 4]);
    const float4 cv = *reinterpret_cast<const float4*>(&out[(size_t)j * D_N + t * 4]);
    float4 gf;
    gf.x = sc * gv.x + 0.01f * cv.x;
    gf.y = sc * gv.y + 0.01f * cv.y;
    gf.z = sc * gv.z + 0.01f * cv.z;
    gf.w = sc * gv.w + 0.01f * cv.w;
    float s = gf.x * gf.x + gf.y * gf.y + gf.z * gf.z + gf.w * gf.w;
#pragma unroll
    for (int off = 32; off >= 1; off >>= 1) s += __shfl_down(s, off, 64);
    __shared__ float wsum[4];
    __shared__ float s_inv;
    if ((t & 63) == 0) wsum[t >> 6] = s;
    __syncthreads();
    if (t == 0) s_inv = 1.0f / fmaxf(sqrtf(wsum[0] + wsum[1] + wsum[2] + wsum[3]), 1e-12f);
    __syncthreads();
    gf.x *= s_inv; gf.y *= s_inv; gf.z *= s_inv; gf.w *= s_inv;
    *reinterpret_cast<float4*>(&out[(size_t)j * D_N + t * 4]) = gf;
}

// ======================= bf16 split prep =======================

__device__ inline u16 f2bf_rtn(float f) {
    unsigned u = __float_as_uint(f);
    unsigned r = u + 0x7fffu + ((u >> 16) & 1u);
    return (u16)(r >> 16);
}
__device__ inline float bf2f(u16 h) { return __uint_as_float(((unsigned)h) << 16); }

__global__ __launch_bounds__(256) void k_split(const float* __restrict__ src,
                                               u16* __restrict__ hi,
                                               u16* __restrict__ lo) {
    const size_t i4 = (size_t)blockIdx.x * 256 + threadIdx.x;
    const float4 v = *reinterpret_cast<const float4*>(&src[i4 * 4]);
    u16 h[4], l[4];
    const float f[4] = {v.x, v.y, v.z, v.w};
#pragma unroll
    for (int j = 0; j < 4; ++j) {
        h[j] = f2bf_rtn(f[j]);
        l[j] = f2bf_rtn(f[j] - bf2f(h[j]));
    }
    *reinterpret_cast<ushort4*>(&hi[i4 * 4]) = make_ushort4(h[0], h[1], h[2], h[3]);
    *reinterpret_cast<ushort4*>(&lo[i4 * 4]) = make_ushort4(l[0], l[1], l[2], l[3]);
}

// ======================= 1-phase/K-tile 256x256 MFMA GEMM + fused argmax ===============
// Virtual K=3072 as 96 tiles of 32: tiles 0-31 -> x_hi.g_hi; 32-63 -> x_lo.g_hi;
// 64-95 -> x_hi.g_lo. mfma_f32_32x32x16_bf16, 8 waves (2M x 4N), per-wave C 128x64.
// LDS 96KB = 3 rotating bufs x (A[256r][32k] 16KB + B[256c][32k] 16KB).
// Swizzle: phys_slot = slot ^ ((row>>1)&3)  (slot = 8-bf16 group; 2 lanes/bank-quad = free).
// Per phase: 12 ds_read_b128 + stage tile K+2 (4 gll, buf (K+2)%3 != live buf)
//            + 16 MFMA + vmcnt(4) + ONE barrier.

#define PHASE(T, BUF, SBUF) do {                                                          \
    const u16* base = lds + (BUF) * 16384;                                                \
    short8 afr[4][2], bfr[2][2];                                                          \
    _Pragma("unroll")                                                                     \
    for (int m = 0; m < 4; ++m) {                                                         \
        afr[m][0] = *reinterpret_cast<const short8*>(base + arow + m * 1024 + aoffk0);    \
        afr[m][1] = *reinterpret_cast<const short8*>(base + arow + m * 1024 + aoffk1);    \
    }                                                                                     \
    _Pragma("unroll")                                                                     \
    for (int n = 0; n < 2; ++n) {                                                         \
        bfr[n][0] = *reinterpret_cast<const short8*>(base + brow + n * 1024 + aoffk0);    \
        bfr[n][1] = *reinterpret_cast<const short8*>(base + brow + n * 1024 + aoffk1);    \
    }                                                                                     \
    STG((T) + 2, SBUF);                                                                   \
    __builtin_amdgcn_s_setprio(1);                                                        \
    _Pragma("unroll")                                                                     \
    for (int ks = 0; ks < 2; ++ks)                                                        \
        _Pragma("unroll")                                                                 \
        for (int m = 0; m < 4; ++m)                                                       \
            _Pragma("unroll")                                                             \
            for (int n = 0; n < 2; ++n)                                                   \
                acc[m][n] = __builtin_amdgcn_mfma_f32_32x32x16_bf16(                      \
                    afr[m][ks], bfr[n][ks], acc[m][n], 0, 0, 0);                          \
    __builtin_amdgcn_s_setprio(0);                                                        \
    asm volatile("s_waitcnt vmcnt(4)" ::: "memory");                                      \
    __builtin_amdgcn_s_barrier();                                                         \
} while (0)

__global__ __launch_bounds__(512, 2) void k_gemm_argmax(
    const u16* __restrict__ x_hi, const u16* __restrict__ x_lo,
    const u16* __restrict__ g_hi, const u16* __restrict__ g_lo,
    const float* __restrict__ invn, u64* __restrict__ pk) {

    __shared__ __align__(16) u16 lds[49152];   // 96 KiB

    const int bid = blockIdx.x;                // 2048 blocks
    const int xcd = bid & 7, lcl = bid >> 3;   // 256 blocks per XCD
    const int mblk = xcd * 8 + ((lcl >> 3) & 7);
    const int nblk = (lcl & 7) + (lcl >> 6) * 8;   // 4x8 patches resident -> L2 reuse
    const int mrow0 = mblk * 256, nrow0 = nblk * 256;

    const int tid = threadIdx.x;
    const int lane = tid & 63;
    const int w = tid >> 6;
    const int wr = w >> 2, wc = w & 3;         // 2x4 wave grid, per-wave C = 128x64

    // ---- fragment-read lane constants ----
    const int l31 = lane & 31, l5 = lane >> 5;
    const int xq = (lane >> 1) & 3;                       // (row>>1)&3 within frag
    const int arow = (wr * 128 + l31) * 32;               // u16
    const int brow = 8192 + (wc * 64 + l31) * 32;         // u16 (B region offset)
    const int aoffk0 = ((0 + l5) ^ xq) * 8;               // ks=0 slot
    const int aoffk1 = ((2 + l5) ^ xq) * 8;               // ks=1 slot

    // ---- staging lane constants (linear LDS dest, pre-permuted source) ----
    const int r0 = tid >> 2;                              // row within 128-row half
    const int xsl = (tid & 3) ^ ((tid >> 3) & 3);         // source logical slot
    const size_t sA = (size_t)(mrow0 + r0) * D_N + xsl * 8;
    const size_t sB = (size_t)(nrow0 + r0) * D_N + xsl * 8;
    const int dstc = (tid & 448) * 8;                     // wave-uniform chunk base (u16)

    auto STG = [&](int T, int buf3) {
        const int Tc = T < NT ? T : NT - 1;    // clamp: redundant rewrite, ledger exact
        const int term = Tc >> 5;
        const u16* xb = (term == 1) ? x_lo : x_hi;
        const u16* gb = (term == 2) ? g_lo : g_hi;
        const int ko = (Tc & 31) * 32;
        u16* da = lds + buf3 * 16384;
        u16* db = da + 8192;
        __builtin_amdgcn_global_load_lds((const AS1 void*)(xb + sA + ko),          (AS3 void*)(da + dstc), 16, 0, 0);
        __builtin_amdgcn_global_load_lds((const AS1 void*)(xb + sA + 131072 + ko), (AS3 void*)(da + 4096 + dstc), 16, 0, 0);
        __builtin_amdgcn_global_load_lds((const AS1 void*)(gb + sB + ko),          (AS3 void*)(db + dstc), 16, 0, 0);
        __builtin_amdgcn_global_load_lds((const AS1 void*)(gb + sB + 131072 + ko), (AS3 void*)(db + 4096 + dstc), 16, 0, 0);
    };

    f32x16 acc[4][2];
#pragma unroll
    for (int m = 0; m < 4; ++m)
#pragma unroll
        for (int n = 0; n < 2; ++n)
#pragma unroll
            for (int r = 0; r < 16; ++r) acc[m][n][r] = 0.0f;

    // prologue: tiles 0 and 1 staged; vmcnt(4) => tile0 landed, tile1 in flight
    STG(0, 0); STG(1, 1);
    asm volatile("s_waitcnt vmcnt(4)" ::: "memory");
    __builtin_amdgcn_s_barrier();

    for (int it = 0; it < 32; ++it) {
        const int T = it * 3;
        PHASE(T,     0, 2);
        PHASE(T + 1, 1, 0);
        PHASE(T + 2, 2, 1);
    }

    // ---------- epilogue: invn-scale + packed argmax -> atomicMax ----------
    float inv[2];
    inv[0] = invn[nrow0 + wc * 64 + l31];
    inv[1] = invn[nrow0 + wc * 64 + 32 + l31];

#pragma unroll
    for (int m = 0; m < 4; ++m) {
#pragma unroll
        for (int r = 0; r < 16; ++r) {
            u64 p = 0;
#pragma unroll
            for (int n = 0; n < 2; ++n) {
                const float v = acc[m][n][r] * inv[n];
                unsigned u = __float_as_uint(v);
                u ^= (u >> 31) ? 0xFFFFFFFFu : 0x80000000u;   // monotone float->uint
                const int col = nrow0 + wc * 64 + n * 32 + l31;
                const u64 cand = ((u64)u << 13) | (unsigned)(8191 - col);  // ties -> smaller col
                p = (cand > p) ? cand : p;
            }
#pragma unroll
            for (int msk = 1; msk < 32; msk <<= 1) {           // reduce over 32 cols
                const u64 o = __shfl_xor(p, msk, 64);
                p = (o > p) ? o : p;
            }
            if (l31 == 0) {
                const int row = mrow0 + wr * 128 + m * 32 + (r & 3) + 8 * (r >> 2) + 4 * l5;
                atomicMax(&pk[row], p);
            }
        }
    }
}

// ======================= fallback fp32 argmax (tiny-ws path) =======================

__global__ __launch_bounds__(256) void k_argmax_fp32(const float* __restrict__ x,
                                                     const float* __restrict__ g,
                                                     const float* __restrict__ invn,
                                                     int* __restrict__ assign) {
    __shared__ __align__(16) float As[32][68];
    __shared__ __align__(16) float Bs[32][68];
    const int t = threadIdx.x;
    const int tx = t & 15;
    const int ty = t >> 4;
    const int row0 = blockIdx.x * 64;
    const int r_a = t >> 3;
    const int c4 = t & 7;
    float bestv[4]; int besti[4];
#pragma unroll
    for (int i = 0; i < 4; ++i) { bestv[i] = -3.0e38f; besti[i] = 0; }
    for (int jt = 0; jt < G_N / 64; ++jt) {
        float acc[4][4] = {};
        for (int kt = 0; kt < D_N / 32; ++kt) {
#pragma unroll
            for (int p = 0; p < 2; ++p) {
                const int r = r_a + p * 32;
                const float4 va = *reinterpret_cast<const float4*>(&x[(size_t)(row0 + r) * D_N + kt * 32 + c4 * 4]);
                As[c4 * 4 + 0][r] = va.x; As[c4 * 4 + 1][r] = va.y; As[c4 * 4 + 2][r] = va.z; As[c4 * 4 + 3][r] = va.w;
                const float4 vb = *reinterpret_cast<const float4*>(&g[(size_t)(jt * 64 + r) * D_N + kt * 32 + c4 * 4]);
                Bs[c4 * 4 + 0][r] = vb.x; Bs[c4 * 4 + 1][r] = vb.y; Bs[c4 * 4 + 2][r] = vb.z; Bs[c4 * 4 + 3][r] = vb.w;
            }
            __syncthreads();
#pragma unroll
            for (int k = 0; k < 32; ++k) {
                const float4 a = *reinterpret_cast<const float4*>(&As[k][ty * 4]);
                const float4 b = *reinterpret_cast<const float4*>(&Bs[k][tx * 4]);
                const float av[4] = {a.x, a.y, a.z, a.w};
                const float bv[4] = {b.x, b.y, b.z, b.w};
#pragma unroll
                for (int i = 0; i < 4; ++i)
#pragma unroll
                    for (int jj = 0; jj < 4; ++jj) acc[i][jj] += av[i] * bv[jj];
            }
            __syncthreads();
        }
#pragma unroll
        for (int jj = 0; jj < 4; ++jj) {
            const int col = jt * 64 + tx * 4 + jj;
            const float s = invn[col];
#pragma unroll
            for (int i = 0; i < 4; ++i) {
                const float v = acc[i][jj] * s;
                if (v > bestv[i]) { bestv[i] = v; besti[i] = col; }
            }
        }
    }
#pragma unroll
    for (int m = 1; m < 16; m <<= 1) {
#pragma unroll
        for (int i = 0; i < 4; ++i) {
            const float ov = __shfl_xor(bestv[i], m, 64);
            const int oi = __shfl_xor(besti[i], m, 64);
            if (ov > bestv[i] || (ov == bestv[i] && oi < besti[i])) { bestv[i] = ov; besti[i] = oi; }
        }
    }
    if (tx == 0) {
#pragma unroll
        for (int i = 0; i < 4; ++i) assign[row0 + ty * 4 + i] = besti[i];
    }
}

__global__ void k_counts_i(const int* __restrict__ assign, int* __restrict__ counts) {
    const int i = blockIdx.x * blockDim.x + threadIdx.x;
    if (i < B_N) atomicAdd(&counts[assign[i]], 1);
}

__global__ __launch_bounds__(256) void k_scatter_i(const float* __restrict__ x,
                                                   const int* __restrict__ assign,
                                                   const int* __restrict__ counts,
                                                   float* __restrict__ contrib) {
    const int i = blockIdx.x;
    const int a = assign[i];
    const float scale = 1.0f / (float)counts[a];
    const int t = threadIdx.x;
    const float4 v = *reinterpret_cast<const float4*>(&x[(size_t)i * D_N + t * 4]);
    float* dst = &contrib[(size_t)a * D_N + t * 4];
    atomicAdd(dst + 0, v.x * scale);
    atomicAdd(dst + 1, v.y * scale);
    atomicAdd(dst + 2, v.z * scale);
    atomicAdd(dst + 3, v.w * scale);
}

// ======================= launch =======================

extern "C" void kernel_launch(void* const* d_in, const int* in_sizes, int n_in,
                              void* d_out, int out_size, void* d_ws, size_t ws_size,
                              hipStream_t stream) {
    const float* x = (const float*)d_in[0];   // [16384, 1024]
    const float* g = (const float*)d_in[1];   // [8192, 1024]
    float* out = (float*)d_out;               // [8192, 1024]; doubles as contrib accumulator

    char* ws = (char*)d_ws;
    u16*  x_hi  = (u16*)(ws);                     // 32 MiB
    u16*  x_lo  = (u16*)(ws + 33554432);          // 32 MiB
    u16*  g_hi  = (u16*)(ws + 67108864);          // 16 MiB
    u16*  g_lo  = (u16*)(ws + 83886080);          // 16 MiB
    float* invn = (float*)(ws + 100663296);       // 32 KiB
    int* counts = (int*)(ws + 100696064);         // 32 KiB
    u64*   pk   = (u64*)(ws + 100728832);         // 128 KiB packed (value|col) per row
    const size_t need = 100859904;

    hipMemsetAsync(out, 0, (size_t)G_N * D_N * sizeof(float), stream);

    if (ws_size >= need) {
        hipMemsetAsync(counts, 0, (size_t)G_N * sizeof(int), stream);
        hipMemsetAsync(pk, 0, (size_t)B_N * sizeof(u64), stream);
        k_norms<<<G_N, 256, 0, stream>>>(g, invn);
        k_split<<<B_N * D_N / 4 / 256, 256, 0, stream>>>(x, x_hi, x_lo);
        k_split<<<G_N * D_N / 4 / 256, 256, 0, stream>>>(g, g_hi, g_lo);
        k_gemm_argmax<<<2048, 512, 0, stream>>>(x_hi, x_lo, g_hi, g_lo, invn, pk);
        k_counts<<<B_N / 256, 256, 0, stream>>>(pk, counts);
        k_scatter<<<B_N, 256, 0, stream>>>(x, pk, counts, out);
        k_finalize<<<G_N, 256, 0, stream>>>(g, counts, out);
    } else {
        // fallback: fp32 vector path (128 KiB scratch)
        float* invn_f = (float*)ws;
        int* assign_f = (int*)(ws + (size_t)G_N * 4);
        int* counts_f = (int*)(ws + (size_t)(G_N + B_N) * 4);
        hipMemsetAsync(counts_f, 0, (size_t)G_N * sizeof(int), stream);
        k_norms<<<G_N, 256, 0, stream>>>(g, invn_f);
        k_argmax_fp32<<<B_N / 64, 256, 0, stream>>>(x, g, invn_f, assign_f);
        k_counts_i<<<B_N / 256, 256, 0, stream>>>(assign_f, counts_f);
        k_scatter_i<<<B_N, 256, 0, stream>>>(x, assign_f, counts_f, out);
        k_finalize<<<G_N, 256, 0, stream>>>(g, counts_f, out);
    }
}

// Round 6
// 1030.330 us; speedup vs baseline: 1.2443x; 1.0748x over previous
//
#include <hip/hip_runtime.h>

#define B_N 16384
#define G_N 8192
#define D_N 1024
#define NT 96   // virtual K = 3072 = 96 K-tiles of 32 (0-31 hi.hi, 32-63 lo.hi, 64-95 hi.lo)

typedef unsigned short u16;
typedef unsigned long long u64;
typedef __attribute__((ext_vector_type(8))) short short8;
typedef __attribute__((ext_vector_type(16))) float f32x16;

#define AS1 __attribute__((address_space(1)))
#define AS3 __attribute__((address_space(3)))

// ======================= common small kernels =======================

__global__ __launch_bounds__(256) void k_norms(const float* __restrict__ g,
                                               float* __restrict__ invn) {
    const int j = blockIdx.x;
    const int t = threadIdx.x;
    const float4 v = *reinterpret_cast<const float4*>(&g[(size_t)j * D_N + t * 4]);
    float s = v.x * v.x + v.y * v.y + v.z * v.z + v.w * v.w;
#pragma unroll
    for (int off = 32; off >= 1; off >>= 1) s += __shfl_down(s, off, 64);
    __shared__ float wsum[4];
    if ((t & 63) == 0) wsum[t >> 6] = s;
    __syncthreads();
    if (t == 0) {
        const float tot = wsum[0] + wsum[1] + wsum[2] + wsum[3];
        invn[j] = 1.0f / fmaxf(sqrtf(tot), 1e-12f);
    }
}

__global__ void k_counts(const u64* __restrict__ pk, int* __restrict__ counts) {
    const int i = blockIdx.x * blockDim.x + threadIdx.x;
    if (i < B_N) {
        const int a = 8191 - (int)(pk[i] & 0x1FFFull);
        atomicAdd(&counts[a], 1);
    }
}

__global__ __launch_bounds__(256) void k_scatter(const float* __restrict__ x,
                                                 const u64* __restrict__ pk,
                                                 const int* __restrict__ counts,
                                                 float* __restrict__ contrib) {
    const int i = blockIdx.x;
    const int a = 8191 - (int)(pk[i] & 0x1FFFull);
    const float scale = 1.0f / (float)counts[a];
    const int t = threadIdx.x;
    const float4 v = *reinterpret_cast<const float4*>(&x[(size_t)i * D_N + t * 4]);
    float* dst = &contrib[(size_t)a * D_N + t * 4];
    atomicAdd(dst + 0, v.x * scale);
    atomicAdd(dst + 1, v.y * scale);
    atomicAdd(dst + 2, v.z * scale);
    atomicAdd(dst + 3, v.w * scale);
}

__global__ __launch_bounds__(256) void k_finalize(const float* __restrict__ g,
                                                  const int* __restrict__ counts,
                                                  float* __restrict__ out) {
    const int j = blockIdx.x;
    const int t = threadIdx.x;
    const float sc = (counts[j] > 0) ? 0.99f : 1.0f;
    const float4 gv = *reinterpret_cast<const float4*>(&g[(size_t)j * D_N + t * 4]);
    const float4 cv = *reinterpret_cast<const float4*>(&out[(size_t)j * D_N + t * 4]);
    float4 gf;
    gf.x = sc * gv.x + 0.01f * cv.x;
    gf.y = sc * gv.y + 0.01f * cv.y;
    gf.z = sc * gv.z + 0.01f * cv.z;
    gf.w = sc * gv.w + 0.01f * cv.w;
    float s = gf.x * gf.x + gf.y * gf.y + gf.z * gf.z + gf.w * gf.w;
#pragma unroll
    for (int off = 32; off >= 1; off >>= 1) s += __shfl_down(s, off, 64);
    __shared__ float wsum[4];
    __shared__ float s_inv;
    if ((t & 63) == 0) wsum[t >> 6] = s;
    __syncthreads();
    if (t == 0) s_inv = 1.0f / fmaxf(sqrtf(wsum[0] + wsum[1] + wsum[2] + wsum[3]), 1e-12f);
    __syncthreads();
    gf.x *= s_inv; gf.y *= s_inv; gf.z *= s_inv; gf.w *= s_inv;
    *reinterpret_cast<float4*>(&out[(size_t)j * D_N + t * 4]) = gf;
}

// ======================= bf16 split + fragment-brick pack =======================
// Packed layout: brick(mu,tau) = rows [mu*32,+32) x k [tau*32,+32), 2KB.
// chunk c (0..127) within brick: ks=c>>6, lane=c&63 -> row=mu*32+(lane&31),
// k = tau*32 + ks*16 + (lane>>5)*8, 8 consecutive bf16 (16B).
// => global_load_lds staging reads CONSECUTIVE 16B chunks (perfect coalescing)
//    into LINEAR LDS, and MFMA frag reads are contiguous 1KiB/wave (0 conflicts).

__device__ inline u16 f2bf_rtn(float f) {
    unsigned u = __float_as_uint(f);
    unsigned r = u + 0x7fffu + ((u >> 16) & 1u);
    return (u16)(r >> 16);
}
__device__ inline float bf2f(u16 h) { return __uint_as_float(((unsigned)h) << 16); }

__global__ __launch_bounds__(256) void k_split_pack(const float* __restrict__ src,
                                                    u16* __restrict__ hi,
                                                    u16* __restrict__ lo) {
    const int id = blockIdx.x * 256 + threadIdx.x;    // packed chunk id
    const int brick = id >> 7, c = id & 127;
    const int mu = brick >> 5, tau = brick & 31;
    const int ks = c >> 6, lane = c & 63;
    const int row = mu * 32 + (lane & 31);
    const int k = tau * 32 + ks * 16 + (lane >> 5) * 8;
    const float* s = src + (size_t)row * D_N + k;
    const float4 v0 = *reinterpret_cast<const float4*>(s);
    const float4 v1 = *reinterpret_cast<const float4*>(s + 4);
    const float f[8] = {v0.x, v0.y, v0.z, v0.w, v1.x, v1.y, v1.z, v1.w};
    short8 h, l;
#pragma unroll
    for (int j = 0; j < 8; ++j) {
        const u16 hj = f2bf_rtn(f[j]);
        h[j] = (short)hj;
        l[j] = (short)f2bf_rtn(f[j] - bf2f(hj));
    }
    *reinterpret_cast<short8*>(hi + (size_t)id * 8) = h;
    *reinterpret_cast<short8*>(lo + (size_t)id * 8) = l;
}

// ======================= pipelined 256x256 MFMA GEMM + fused argmax =======================
// mfma_f32_32x32x16_bf16, 8 waves (2M x 4N), per-wave C 128x64. BK=32.
// LDS 96KB = 3 rotating bufs x (A 16KB + B 16KB), fragment-brick order (linear).
// Register double-buffered fragments: body p = { vmcnt(0); barrier; STG(p+2);
//   ds_read tile p+1 -> set[(p+1)&1]; MFMA tile p on set[p&1] }.
// MFMA never waits on this body's reads (lgkmcnt(12) counted wait) -> LDS port
// service overlaps the MFMA block. ONE barrier per K-tile.

#define MFMA_BLK(S) do {                                                                   \
    __builtin_amdgcn_s_setprio(1);                                                         \
    _Pragma("unroll")                                                                      \
    for (int ks = 0; ks < 2; ++ks)                                                         \
        _Pragma("unroll")                                                                  \
        for (int m = 0; m < 4; ++m)                                                        \
            _Pragma("unroll")                                                              \
            for (int n = 0; n < 2; ++n)                                                    \
                acc[m][n] = __builtin_amdgcn_mfma_f32_32x32x16_bf16(                       \
                    afr[S][m][ks], bfr[S][n][ks], acc[m][n], 0, 0, 0);                     \
    __builtin_amdgcn_s_setprio(0);                                                         \
} while (0)

#define READS(BUF, S) do {                                                                 \
    const u16* aB = lds + (BUF) * 16384 + aRd;                                             \
    const u16* bB = lds + (BUF) * 16384 + 8192 + bRd;                                      \
    _Pragma("unroll")                                                                      \
    for (int m = 0; m < 4; ++m)                                                            \
        _Pragma("unroll")                                                                  \
        for (int ks = 0; ks < 2; ++ks)                                                     \
            afr[S][m][ks] = *reinterpret_cast<const short8*>(aB + m * 1024 + ks * 512);    \
    _Pragma("unroll")                                                                      \
    for (int n = 0; n < 2; ++n)                                                            \
        _Pragma("unroll")                                                                  \
        for (int ks = 0; ks < 2; ++ks)                                                     \
            bfr[S][n][ks] = *reinterpret_cast<const short8*>(bB + n * 1024 + ks * 512);    \
} while (0)

#define BODY(P, BSTG, BRD, SM, SR) do {                                                    \
    asm volatile("s_waitcnt vmcnt(0)" ::: "memory");                                       \
    __builtin_amdgcn_s_barrier();                                                          \
    STG((P) + 2, BSTG);                                                                    \
    READS(BRD, SR);                                                                        \
    MFMA_BLK(SM);                                                                          \
} while (0)

__global__ __launch_bounds__(512, 2) void k_gemm_argmax(
    const u16* __restrict__ x_hi, const u16* __restrict__ x_lo,
    const u16* __restrict__ g_hi, const u16* __restrict__ g_lo,
    const float* __restrict__ invn, u64* __restrict__ pk) {

    __shared__ __align__(16) u16 lds[49152];   // 96 KiB: 3 bufs x 32KB

    const int bid = blockIdx.x;                // 2048 blocks
    const int xcd = bid & 7, lcl = bid >> 3;
    const int mblk = xcd * 8 + ((lcl >> 3) & 7);
    const int nblk = (lcl & 7) + (lcl >> 6) * 8;   // 4x8 patches resident per XCD
    const int mrow0 = mblk * 256, nrow0 = nblk * 256;

    const int tid = threadIdx.x;
    const int lane = tid & 63;
    const int w = tid >> 6;
    const int wr = w >> 2, wc = w & 3;         // 2x4 wave grid, per-wave C = 128x64
    const int l31 = lane & 31, l5 = lane >> 5;

    // fragment-read bases (contiguous 1KiB per wave per frag -> conflict-free)
    const int aRd = (wr * 512 + lane) * 8;     // u16
    const int bRd = (wc * 256 + lane) * 8;     // u16 (relative to B region)

    // staging constants: thread tid stages packed chunks c=tid and c=tid+512
    const int wub = (tid & 448) * 8;           // wave-uniform LDS chunk base (u16)
    const int cOff = (tid & 127) * 8;          // within-brick chunk offset (u16)
    const int brkA = tid >> 7;                 // local brick 0..3 (+4 for 2nd load)
    const size_t aBase = ((size_t)(mblk * 8 + brkA)) * 32768 + cOff;
    const size_t bBase = ((size_t)(nblk * 8 + brkA)) * 32768 + cOff;

    auto STG = [&](int T, int buf) {
        const int Tc = T < NT ? T : NT - 1;    // clamp: redundant rewrite, ledger exact
        const int term = Tc >> 5;
        const int tko = (Tc & 31) * 1024;      // tau * brick-stride (u16)
        const u16* xa = ((term == 1) ? x_lo : x_hi) + aBase + tko;
        const u16* gb = ((term == 2) ? g_lo : g_hi) + bBase + tko;
        u16* da = lds + buf * 16384 + wub;
        u16* db = da + 8192;
        __builtin_amdgcn_global_load_lds((const AS1 void*)xa,            (AS3 void*)da, 16, 0, 0);
        __builtin_amdgcn_global_load_lds((const AS1 void*)(xa + 131072), (AS3 void*)(da + 4096), 16, 0, 0);
        __builtin_amdgcn_global_load_lds((const AS1 void*)gb,            (AS3 void*)db, 16, 0, 0);
        __builtin_amdgcn_global_load_lds((const AS1 void*)(gb + 131072), (AS3 void*)(db + 4096), 16, 0, 0);
    };

    f32x16 acc[4][2];
#pragma unroll
    for (int m = 0; m < 4; ++m)
#pragma unroll
        for (int n = 0; n < 2; ++n)
#pragma unroll
            for (int r = 0; r < 16; ++r) acc[m][n][r] = 0.0f;

    short8 afr[2][4][2], bfr[2][2][2];         // double-buffered fragment sets

    // prologue: stage tiles 0,1; wait tile 0 landed; load tile 0 fragments
    STG(0, 0); STG(1, 1);
    asm volatile("s_waitcnt vmcnt(4)" ::: "memory");
    __builtin_amdgcn_s_barrier();
    READS(0, 0);

    for (int it = 0; it < 16; ++it) {
        const int p = it * 6;
        BODY(p,     2, 1, 0, 1);
        BODY(p + 1, 0, 2, 1, 0);
        BODY(p + 2, 1, 0, 0, 1);
        BODY(p + 3, 2, 1, 1, 0);
        BODY(p + 4, 0, 2, 0, 1);
        BODY(p + 5, 1, 0, 1, 0);
    }

    // ---------- epilogue: invn-scale + packed argmax -> atomicMax ----------
    float inv[2];
    inv[0] = invn[nrow0 + wc * 64 + l31];
    inv[1] = invn[nrow0 + wc * 64 + 32 + l31];

#pragma unroll
    for (int m = 0; m < 4; ++m) {
#pragma unroll
        for (int r = 0; r < 16; ++r) {
            u64 p = 0;
#pragma unroll
            for (int n = 0; n < 2; ++n) {
                const float v = acc[m][n][r] * inv[n];
                unsigned u = __float_as_uint(v);
                u ^= (u >> 31) ? 0xFFFFFFFFu : 0x80000000u;   // monotone float->uint
                const int col = nrow0 + wc * 64 + n * 32 + l31;
                const u64 cand = ((u64)u << 13) | (unsigned)(8191 - col);  // ties -> smaller col
                p = (cand > p) ? cand : p;
            }
#pragma unroll
            for (int msk = 1; msk < 32; msk <<= 1) {
                const u64 o = __shfl_xor(p, msk, 64);
                p = (o > p) ? o : p;
            }
            if (l31 == 0) {
                const int row = mrow0 + wr * 128 + m * 32 + (r & 3) + 8 * (r >> 2) + 4 * l5;
                atomicMax(&pk[row], p);
            }
        }
    }
}

// ======================= fallback fp32 argmax (tiny-ws path) =======================

__global__ __launch_bounds__(256) void k_argmax_fp32(const float* __restrict__ x,
                                                     const float* __restrict__ g,
                                                     const float* __restrict__ invn,
                                                     int* __restrict__ assign) {
    __shared__ __align__(16) float As[32][68];
    __shared__ __align__(16) float Bs[32][68];
    const int t = threadIdx.x;
    const int tx = t & 15;
    const int ty = t >> 4;
    const int row0 = blockIdx.x * 64;
    const int r_a = t >> 3;
    const int c4 = t & 7;
    float bestv[4]; int besti[4];
#pragma unroll
    for (int i = 0; i < 4; ++i) { bestv[i] = -3.0e38f; besti[i] = 0; }
    for (int jt = 0; jt < G_N / 64; ++jt) {
        float acc[4][4] = {};
        for (int kt = 0; kt < D_N / 32; ++kt) {
#pragma unroll
            for (int p = 0; p < 2; ++p) {
                const int r = r_a + p * 32;
                const float4 va = *reinterpret_cast<const float4*>(&x[(size_t)(row0 + r) * D_N + kt * 32 + c4 * 4]);
                As[c4 * 4 + 0][r] = va.x; As[c4 * 4 + 1][r] = va.y; As[c4 * 4 + 2][r] = va.z; As[c4 * 4 + 3][r] = va.w;
                const float4 vb = *reinterpret_cast<const float4*>(&g[(size_t)(jt * 64 + r) * D_N + kt * 32 + c4 * 4]);
                Bs[c4 * 4 + 0][r] = vb.x; Bs[c4 * 4 + 1][r] = vb.y; Bs[c4 * 4 + 2][r] = vb.z; Bs[c4 * 4 + 3][r] = vb.w;
            }
            __syncthreads();
#pragma unroll
            for (int k = 0; k < 32; ++k) {
                const float4 a = *reinterpret_cast<const float4*>(&As[k][ty * 4]);
                const float4 b = *reinterpret_cast<const float4*>(&Bs[k][tx * 4]);
                const float av[4] = {a.x, a.y, a.z, a.w};
                const float bv[4] = {b.x, b.y, b.z, b.w};
#pragma unroll
                for (int i = 0; i < 4; ++i)
#pragma unroll
                    for (int jj = 0; jj < 4; ++jj) acc[i][jj] += av[i] * bv[jj];
            }
            __syncthreads();
        }
#pragma unroll
        for (int jj = 0; jj < 4; ++jj) {
            const int col = jt * 64 + tx * 4 + jj;
            const float s = invn[col];
#pragma unroll
            for (int i = 0; i < 4; ++i) {
                const float v = acc[i][jj] * s;
                if (v > bestv[i]) { bestv[i] = v; besti[i] = col; }
            }
        }
    }
#pragma unroll
    for (int m = 1; m < 16; m <<= 1) {
#pragma unroll
        for (int i = 0; i < 4; ++i) {
            const float ov = __shfl_xor(bestv[i], m, 64);
            const int oi = __shfl_xor(besti[i], m, 64);
            if (ov > bestv[i] || (ov == bestv[i] && oi < besti[i])) { bestv[i] = ov; besti[i] = oi; }
        }
    }
    if (tx == 0) {
#pragma unroll
        for (int i = 0; i < 4; ++i) assign[row0 + ty * 4 + i] = besti[i];
    }
}

__global__ void k_counts_i(const int* __restrict__ assign, int* __restrict__ counts) {
    const int i = blockIdx.x * blockDim.x + threadIdx.x;
    if (i < B_N) atomicAdd(&counts[assign[i]], 1);
}

__global__ __launch_bounds__(256) void k_scatter_i(const float* __restrict__ x,
                                                   const int* __restrict__ assign,
                                                   const int* __restrict__ counts,
                                                   float* __restrict__ contrib) {
    const int i = blockIdx.x;
    const int a = assign[i];
    const float scale = 1.0f / (float)counts[a];
    const int t = threadIdx.x;
    const float4 v = *reinterpret_cast<const float4*>(&x[(size_t)i * D_N + t * 4]);
    float* dst = &contrib[(size_t)a * D_N + t * 4];
    atomicAdd(dst + 0, v.x * scale);
    atomicAdd(dst + 1, v.y * scale);
    atomicAdd(dst + 2, v.z * scale);
    atomicAdd(dst + 3, v.w * scale);
}

// ======================= launch =======================

extern "C" void kernel_launch(void* const* d_in, const int* in_sizes, int n_in,
                              void* d_out, int out_size, void* d_ws, size_t ws_size,
                              hipStream_t stream) {
    const float* x = (const float*)d_in[0];   // [16384, 1024]
    const float* g = (const float*)d_in[1];   // [8192, 1024]
    float* out = (float*)d_out;               // [8192, 1024]; doubles as contrib accumulator

    char* ws = (char*)d_ws;
    u16*  x_hi  = (u16*)(ws);                     // 32 MiB (packed bricks)
    u16*  x_lo  = (u16*)(ws + 33554432);          // 32 MiB
    u16*  g_hi  = (u16*)(ws + 67108864);          // 16 MiB
    u16*  g_lo  = (u16*)(ws + 83886080);          // 16 MiB
    float* invn = (float*)(ws + 100663296);       // 32 KiB
    int* counts = (int*)(ws + 100696064);         // 32 KiB
    u64*   pk   = (u64*)(ws + 100728832);         // 128 KiB packed (value|col) per row
    const size_t need = 100859904;

    hipMemsetAsync(out, 0, (size_t)G_N * D_N * sizeof(float), stream);

    if (ws_size >= need) {
        hipMemsetAsync(counts, 0, (size_t)G_N * sizeof(int), stream);
        hipMemsetAsync(pk, 0, (size_t)B_N * sizeof(u64), stream);
        k_norms<<<G_N, 256, 0, stream>>>(g, invn);
        k_split_pack<<<B_N * D_N / 8 / 256, 256, 0, stream>>>(x, x_hi, x_lo);
        k_split_pack<<<G_N * D_N / 8 / 256, 256, 0, stream>>>(g, g_hi, g_lo);
        k_gemm_argmax<<<2048, 512, 0, stream>>>(x_hi, x_lo, g_hi, g_lo, invn, pk);
        k_counts<<<B_N / 256, 256, 0, stream>>>(pk, counts);
        k_scatter<<<B_N, 256, 0, stream>>>(x, pk, counts, out);
        k_finalize<<<G_N, 256, 0, stream>>>(g, counts, out);
    } else {
        // fallback: fp32 vector path (128 KiB scratch)
        float* invn_f = (float*)ws;
        int* assign_f = (int*)(ws + (size_t)G_N * 4);
        int* counts_f = (int*)(ws + (size_t)(G_N + B_N) * 4);
        hipMemsetAsync(counts_f, 0, (size_t)G_N * sizeof(int), stream);
        k_norms<<<G_N, 256, 0, stream>>>(g, invn_f);
        k_argmax_fp32<<<B_N / 64, 256, 0, stream>>>(x, g, invn_f, assign_f);
        k_counts_i<<<B_N / 256, 256, 0, stream>>>(assign_f, counts_f);
        k_scatter_i<<<B_N, 256, 0, stream>>>(x, assign_f, counts_f, out);
        k_finalize<<<G_N, 256, 0, stream>>>(g, counts_f, out);
    }
}

// Round 7
// 1026.558 us; speedup vs baseline: 1.2489x; 1.0037x over previous
//
#include <hip/hip_runtime.h>

#define B_N 16384
#define G_N 8192
#define D_N 1024
#define NT 96   // virtual K = 3072 = 96 K-tiles of 32 (0-31 hi.hi, 32-63 lo.hi, 64-95 hi.lo)

typedef unsigned short u16;
typedef unsigned long long u64;
typedef __attribute__((ext_vector_type(8))) short short8;
typedef __attribute__((ext_vector_type(16))) float f32x16;

#define AS1 __attribute__((address_space(1)))
#define AS3 __attribute__((address_space(3)))

// ======================= common small kernels =======================

__global__ __launch_bounds__(256) void k_norms(const float* __restrict__ g,
                                               float* __restrict__ invn) {
    const int j = blockIdx.x;
    const int t = threadIdx.x;
    const float4 v = *reinterpret_cast<const float4*>(&g[(size_t)j * D_N + t * 4]);
    float s = v.x * v.x + v.y * v.y + v.z * v.z + v.w * v.w;
#pragma unroll
    for (int off = 32; off >= 1; off >>= 1) s += __shfl_down(s, off, 64);
    __shared__ float wsum[4];
    if ((t & 63) == 0) wsum[t >> 6] = s;
    __syncthreads();
    if (t == 0) {
        const float tot = wsum[0] + wsum[1] + wsum[2] + wsum[3];
        invn[j] = 1.0f / fmaxf(sqrtf(tot), 1e-12f);
    }
}

__global__ void k_counts(const u64* __restrict__ pk, int* __restrict__ counts) {
    const int i = blockIdx.x * blockDim.x + threadIdx.x;
    if (i < B_N) {
        const int a = 8191 - (int)(pk[i] & 0x1FFFull);
        atomicAdd(&counts[a], 1);
    }
}

__global__ __launch_bounds__(256) void k_scatter(const float* __restrict__ x,
                                                 const u64* __restrict__ pk,
                                                 const int* __restrict__ counts,
                                                 float* __restrict__ contrib) {
    const int i = blockIdx.x;
    const int a = 8191 - (int)(pk[i] & 0x1FFFull);
    const float scale = 1.0f / (float)counts[a];
    const int t = threadIdx.x;
    const float4 v = *reinterpret_cast<const float4*>(&x[(size_t)i * D_N + t * 4]);
    float* dst = &contrib[(size_t)a * D_N + t * 4];
    atomicAdd(dst + 0, v.x * scale);
    atomicAdd(dst + 1, v.y * scale);
    atomicAdd(dst + 2, v.z * scale);
    atomicAdd(dst + 3, v.w * scale);
}

__global__ __launch_bounds__(256) void k_finalize(const float* __restrict__ g,
                                                  const int* __restrict__ counts,
                                                  float* __restrict__ out) {
    const int j = blockIdx.x;
    const int t = threadIdx.x;
    const float sc = (counts[j] > 0) ? 0.99f : 1.0f;
    const float4 gv = *reinterpret_cast<const float4*>(&g[(size_t)j * D_N + t * 4]);
    const float4 cv = *reinterpret_cast<const float4*>(&out[(size_t)j * D_N + t * 4]);
    float4 gf;
    gf.x = sc * gv.x + 0.01f * cv.x;
    gf.y = sc * gv.y + 0.01f * cv.y;
    gf.z = sc * gv.z + 0.01f * cv.z;
    gf.w = sc * gv.w + 0.01f * cv.w;
    float s = gf.x * gf.x + gf.y * gf.y + gf.z * gf.z + gf.w * gf.w;
#pragma unroll
    for (int off = 32; off >= 1; off >>= 1) s += __shfl_down(s, off, 64);
    __shared__ float wsum[4];
    __shared__ float s_inv;
    if ((t & 63) == 0) wsum[t >> 6] = s;
    __syncthreads();
    if (t == 0) s_inv = 1.0f / fmaxf(sqrtf(wsum[0] + wsum[1] + wsum[2] + wsum[3]), 1e-12f);
    __syncthreads();
    gf.x *= s_inv; gf.y *= s_inv; gf.z *= s_inv; gf.w *= s_inv;
    *reinterpret_cast<float4*>(&out[(size_t)j * D_N + t * 4]) = gf;
}

// ======================= bf16 split + fragment-brick pack =======================

__device__ inline u16 f2bf_rtn(float f) {
    unsigned u = __float_as_uint(f);
    unsigned r = u + 0x7fffu + ((u >> 16) & 1u);
    return (u16)(r >> 16);
}
__device__ inline float bf2f(u16 h) { return __uint_as_float(((unsigned)h) << 16); }

__global__ __launch_bounds__(256) void k_split_pack(const float* __restrict__ src,
                                                    u16* __restrict__ hi,
                                                    u16* __restrict__ lo) {
    const int id = blockIdx.x * 256 + threadIdx.x;    // packed chunk id
    const int brick = id >> 7, c = id & 127;
    const int mu = brick >> 5, tau = brick & 31;
    const int ks = c >> 6, lane = c & 63;
    const int row = mu * 32 + (lane & 31);
    const int k = tau * 32 + ks * 16 + (lane >> 5) * 8;
    const float* s = src + (size_t)row * D_N + k;
    const float4 v0 = *reinterpret_cast<const float4*>(s);
    const float4 v1 = *reinterpret_cast<const float4*>(s + 4);
    const float f[8] = {v0.x, v0.y, v0.z, v0.w, v1.x, v1.y, v1.z, v1.w};
    short8 h, l;
#pragma unroll
    for (int j = 0; j < 8; ++j) {
        const u16 hj = f2bf_rtn(f[j]);
        h[j] = (short)hj;
        l[j] = (short)f2bf_rtn(f[j] - bf2f(hj));
    }
    *reinterpret_cast<short8*>(hi + (size_t)id * 8) = h;
    *reinterpret_cast<short8*>(lo + (size_t)id * 8) = l;
}

// ======================= pipelined 256x256 MFMA GEMM + fused argmax =======================
// mfma_f32_32x32x16_bf16, 8 waves (2M x 4N), per-wave C 128x64. BK=32.
// LDS 128KB = 4 rotating bufs x (A 16KB + B 16KB), fragment-brick order (linear).
// Stage 3 tiles ahead; body q = { vmcnt(4) [completes STG(q+1)]; barrier;
//   STG(q+3); ds_read tile q+1 -> set[(q+1)&1]; MFMA tile q on set[q&1] },
// with sched_group_barrier pinning a 1:1 DS_READ/MFMA interleave (LDS port
// grinds under the matrix pipe). Counted vmcnt only - never drained to 0.

#define MFMA_BLK(S) do {                                                                   \
    _Pragma("unroll")                                                                      \
    for (int ks = 0; ks < 2; ++ks)                                                         \
        _Pragma("unroll")                                                                  \
        for (int m = 0; m < 4; ++m)                                                        \
            _Pragma("unroll")                                                              \
            for (int n = 0; n < 2; ++n)                                                    \
                acc[m][n] = __builtin_amdgcn_mfma_f32_32x32x16_bf16(                       \
                    afr[S][m][ks], bfr[S][n][ks], acc[S][m][ks], 0, 0, 0);                 \
} while (0)

// NOTE: acc index fixed below (macro redefined) - see BODY usage.
#undef MFMA_BLK
#define MFMA_BLK(S) do {                                                                   \
    _Pragma("unroll")                                                                      \
    for (int ks = 0; ks < 2; ++ks)                                                         \
        _Pragma("unroll")                                                                  \
        for (int m = 0; m < 4; ++m)                                                        \
            _Pragma("unroll")                                                              \
            for (int n = 0; n < 2; ++n)                                                    \
                acc[m][n] = __builtin_amdgcn_mfma_f32_32x32x16_bf16(                       \
                    afr[S][m][ks], bfr[S][n][ks], acc[m][n], 0, 0, 0);                     \
} while (0)

#define READS(BUF, S) do {                                                                 \
    const u16* aB = lds + (BUF) * 16384 + aRd;                                             \
    const u16* bB = lds + (BUF) * 16384 + 8192 + bRd;                                      \
    _Pragma("unroll")                                                                      \
    for (int m = 0; m < 4; ++m)                                                            \
        _Pragma("unroll")                                                                  \
        for (int ks = 0; ks < 2; ++ks)                                                     \
            afr[S][m][ks] = *reinterpret_cast<const short8*>(aB + m * 1024 + ks * 512);    \
    _Pragma("unroll")                                                                      \
    for (int n = 0; n < 2; ++n)                                                            \
        _Pragma("unroll")                                                                  \
        for (int ks = 0; ks < 2; ++ks)                                                     \
            bfr[S][n][ks] = *reinterpret_cast<const short8*>(bB + n * 1024 + ks * 512);    \
} while (0)

// sched_group_barrier masks: MFMA=0x8, VMEM|VMEM_READ|VMEM_WRITE=0x70, DS_READ=0x100
#define SGB __builtin_amdgcn_sched_group_barrier

#define BODY(P, BSTG, BRD, SM, SR) do {                                                    \
    asm volatile("s_waitcnt vmcnt(4)" ::: "memory");                                       \
    __builtin_amdgcn_s_barrier();                                                          \
    STG((P) + 3, BSTG);                                                                    \
    READS(BRD, SR);                                                                        \
    __builtin_amdgcn_s_setprio(1);                                                         \
    MFMA_BLK(SM);                                                                          \
    __builtin_amdgcn_s_setprio(0);                                                         \
    _Pragma("unroll")                                                                      \
    for (int q = 0; q < 12; ++q) { SGB(0x100, 1, 0); SGB(0x008, 1, 0); }                   \
    SGB(0x008, 4, 0);                                                                      \
    SGB(0x070, 4, 0);                                                                      \
} while (0)

__global__ __launch_bounds__(512, 2) void k_gemm_argmax(
    const u16* __restrict__ x_hi, const u16* __restrict__ x_lo,
    const u16* __restrict__ g_hi, const u16* __restrict__ g_lo,
    const float* __restrict__ invn, u64* __restrict__ pk) {

    __shared__ __align__(16) u16 lds[65536];   // 128 KiB: 4 bufs x 32KB

    const int bid = blockIdx.x;                // 2048 blocks
    const int xcd = bid & 7, lcl = bid >> 3;
    const int mblk = xcd * 8 + ((lcl >> 3) & 7);
    const int nblk = (lcl & 7) + (lcl >> 6) * 8;   // 4x8 patches resident per XCD
    const int mrow0 = mblk * 256, nrow0 = nblk * 256;

    const int tid = threadIdx.x;
    const int lane = tid & 63;
    const int w = tid >> 6;
    const int wr = w >> 2, wc = w & 3;         // 2x4 wave grid, per-wave C = 128x64
    const int l31 = lane & 31, l5 = lane >> 5;

    // fragment-read bases (contiguous 1KiB per wave per frag -> conflict-free)
    const int aRd = (wr * 512 + lane) * 8;     // u16
    const int bRd = (wc * 256 + lane) * 8;     // u16 (relative to B region)

    // staging constants: thread tid stages packed chunks c=tid and c=tid+512
    const int wub = (tid & 448) * 8;           // wave-uniform LDS chunk base (u16)
    const int cOff = (tid & 127) * 8;          // within-brick chunk offset (u16)
    const int brkA = tid >> 7;                 // local brick 0..3 (+4 for 2nd load)
    const size_t aBase = ((size_t)(mblk * 8 + brkA)) * 32768 + cOff;
    const size_t bBase = ((size_t)(nblk * 8 + brkA)) * 32768 + cOff;

    auto STG = [&](int T, int buf) {
        const int Tc = T < NT ? T : NT - 1;    // clamp: redundant rewrite, ledger exact
        const int term = Tc >> 5;
        const int tko = (Tc & 31) * 1024;      // tau * brick-stride (u16)
        const u16* xa = ((term == 1) ? x_lo : x_hi) + aBase + tko;
        const u16* gb = ((term == 2) ? g_lo : g_hi) + bBase + tko;
        u16* da = lds + buf * 16384 + wub;
        u16* db = da + 8192;
        __builtin_amdgcn_global_load_lds((const AS1 void*)xa,            (AS3 void*)da, 16, 0, 0);
        __builtin_amdgcn_global_load_lds((const AS1 void*)(xa + 131072), (AS3 void*)(da + 4096), 16, 0, 0);
        __builtin_amdgcn_global_load_lds((const AS1 void*)gb,            (AS3 void*)db, 16, 0, 0);
        __builtin_amdgcn_global_load_lds((const AS1 void*)(gb + 131072), (AS3 void*)(db + 4096), 16, 0, 0);
    };

    f32x16 acc[4][2];
#pragma unroll
    for (int m = 0; m < 4; ++m)
#pragma unroll
        for (int n = 0; n < 2; ++n)
#pragma unroll
            for (int r = 0; r < 16; ++r) acc[m][n][r] = 0.0f;

    short8 afr[2][4][2], bfr[2][2][2];         // double-buffered fragment sets

    // prologue: stage tiles 0,1,2 (12 loads out); wait tile 0; read tile 0 frags
    STG(0, 0); STG(1, 1); STG(2, 2);
    asm volatile("s_waitcnt vmcnt(8)" ::: "memory");
    __builtin_amdgcn_s_barrier();
    READS(0, 0);

    for (int it = 0; it < 24; ++it) {
        const int p = it * 4;
        // body q: STG(q+3)->buf (q+3)&3, READS tile q+1 from buf (q+1)&3 -> set (q+1)&1,
        //         MFMA tile q on set q&1
        BODY(p,     3, 1, 0, 1);
        BODY(p + 1, 0, 2, 1, 0);
        BODY(p + 2, 1, 3, 0, 1);
        BODY(p + 3, 2, 0, 1, 0);
    }

    // ---------- epilogue: invn-scale + packed argmax -> atomicMax ----------
    float inv[2];
    inv[0] = invn[nrow0 + wc * 64 + l31];
    inv[1] = invn[nrow0 + wc * 64 + 32 + l31];

#pragma unroll
    for (int m = 0; m < 4; ++m) {
#pragma unroll
        for (int r = 0; r < 16; ++r) {
            u64 p = 0;
#pragma unroll
            for (int n = 0; n < 2; ++n) {
                const float v = acc[m][n][r] * inv[n];
                unsigned u = __float_as_uint(v);
                u ^= (u >> 31) ? 0xFFFFFFFFu : 0x80000000u;   // monotone float->uint
                const int col = nrow0 + wc * 64 + n * 32 + l31;
                const u64 cand = ((u64)u << 13) | (unsigned)(8191 - col);  // ties -> smaller col
                p = (cand > p) ? cand : p;
            }
#pragma unroll
            for (int msk = 1; msk < 32; msk <<= 1) {
                const u64 o = __shfl_xor(p, msk, 64);
                p = (o > p) ? o : p;
            }
            if (l31 == 0) {
                const int row = mrow0 + wr * 128 + m * 32 + (r & 3) + 8 * (r >> 2) + 4 * l5;
                atomicMax(&pk[row], p);
            }
        }
    }
}

// ======================= fallback fp32 argmax (tiny-ws path) =======================

__global__ __launch_bounds__(256) void k_argmax_fp32(const float* __restrict__ x,
                                                     const float* __restrict__ g,
                                                     const float* __restrict__ invn,
                                                     int* __restrict__ assign) {
    __shared__ __align__(16) float As[32][68];
    __shared__ __align__(16) float Bs[32][68];
    const int t = threadIdx.x;
    const int tx = t & 15;
    const int ty = t >> 4;
    const int row0 = blockIdx.x * 64;
    const int r_a = t >> 3;
    const int c4 = t & 7;
    float bestv[4]; int besti[4];
#pragma unroll
    for (int i = 0; i < 4; ++i) { bestv[i] = -3.0e38f; besti[i] = 0; }
    for (int jt = 0; jt < G_N / 64; ++jt) {
        float acc[4][4] = {};
        for (int kt = 0; kt < D_N / 32; ++kt) {
#pragma unroll
            for (int p = 0; p < 2; ++p) {
                const int r = r_a + p * 32;
                const float4 va = *reinterpret_cast<const float4*>(&x[(size_t)(row0 + r) * D_N + kt * 32 + c4 * 4]);
                As[c4 * 4 + 0][r] = va.x; As[c4 * 4 + 1][r] = va.y; As[c4 * 4 + 2][r] = va.z; As[c4 * 4 + 3][r] = va.w;
                const float4 vb = *reinterpret_cast<const float4*>(&g[(size_t)(jt * 64 + r) * D_N + kt * 32 + c4 * 4]);
                Bs[c4 * 4 + 0][r] = vb.x; Bs[c4 * 4 + 1][r] = vb.y; Bs[c4 * 4 + 2][r] = vb.z; Bs[c4 * 4 + 3][r] = vb.w;
            }
            __syncthreads();
#pragma unroll
            for (int k = 0; k < 32; ++k) {
                const float4 a = *reinterpret_cast<const float4*>(&As[k][ty * 4]);
                const float4 b = *reinterpret_cast<const float4*>(&Bs[k][tx * 4]);
                const float av[4] = {a.x, a.y, a.z, a.w};
                const float bv[4] = {b.x, b.y, b.z, b.w};
#pragma unroll
                for (int i = 0; i < 4; ++i)
#pragma unroll
                    for (int jj = 0; jj < 4; ++jj) acc[i][jj] += av[i] * bv[jj];
            }
            __syncthreads();
        }
#pragma unroll
        for (int jj = 0; jj < 4; ++jj) {
            const int col = jt * 64 + tx * 4 + jj;
            const float s = invn[col];
#pragma unroll
            for (int i = 0; i < 4; ++i) {
                const float v = acc[i][jj] * s;
                if (v > bestv[i]) { bestv[i] = v; besti[i] = col; }
            }
        }
    }
#pragma unroll
    for (int m = 1; m < 16; m <<= 1) {
#pragma unroll
        for (int i = 0; i < 4; ++i) {
            const float ov = __shfl_xor(bestv[i], m, 64);
            const int oi = __shfl_xor(besti[i], m, 64);
            if (ov > bestv[i] || (ov == bestv[i] && oi < besti[i])) { bestv[i] = ov; besti[i] = oi; }
        }
    }
    if (tx == 0) {
#pragma unroll
        for (int i = 0; i < 4; ++i) assign[row0 + ty * 4 + i] = besti[i];
    }
}

__global__ void k_counts_i(const int* __restrict__ assign, int* __restrict__ counts) {
    const int i = blockIdx.x * blockDim.x + threadIdx.x;
    if (i < B_N) atomicAdd(&counts[assign[i]], 1);
}

__global__ __launch_bounds__(256) void k_scatter_i(const float* __restrict__ x,
                                                   const int* __restrict__ assign,
                                                   const int* __restrict__ counts,
                                                   float* __restrict__ contrib) {
    const int i = blockIdx.x;
    const int a = assign[i];
    const float scale = 1.0f / (float)counts[a];
    const int t = threadIdx.x;
    const float4 v = *reinterpret_cast<const float4*>(&x[(size_t)i * D_N + t * 4]);
    float* dst = &contrib[(size_t)a * D_N + t * 4];
    atomicAdd(dst + 0, v.x * scale);
    atomicAdd(dst + 1, v.y * scale);
    atomicAdd(dst + 2, v.z * scale);
    atomicAdd(dst + 3, v.w * scale);
}

// ======================= launch =======================

extern "C" void kernel_launch(void* const* d_in, const int* in_sizes, int n_in,
                              void* d_out, int out_size, void* d_ws, size_t ws_size,
                              hipStream_t stream) {
    const float* x = (const float*)d_in[0];   // [16384, 1024]
    const float* g = (const float*)d_in[1];   // [8192, 1024]
    float* out = (float*)d_out;               // [8192, 1024]; doubles as contrib accumulator

    char* ws = (char*)d_ws;
    u16*  x_hi  = (u16*)(ws);                     // 32 MiB (packed bricks)
    u16*  x_lo  = (u16*)(ws + 33554432);          // 32 MiB
    u16*  g_hi  = (u16*)(ws + 67108864);          // 16 MiB
    u16*  g_lo  = (u16*)(ws + 83886080);          // 16 MiB
    float* invn = (float*)(ws + 100663296);       // 32 KiB
    int* counts = (int*)(ws + 100696064);         // 32 KiB
    u64*   pk   = (u64*)(ws + 100728832);         // 128 KiB packed (value|col) per row
    const size_t need = 100859904;

    hipMemsetAsync(out, 0, (size_t)G_N * D_N * sizeof(float), stream);

    if (ws_size >= need) {
        hipMemsetAsync(counts, 0, (size_t)G_N * sizeof(int), stream);
        hipMemsetAsync(pk, 0, (size_t)B_N * sizeof(u64), stream);
        k_norms<<<G_N, 256, 0, stream>>>(g, invn);
        k_split_pack<<<B_N * D_N / 8 / 256, 256, 0, stream>>>(x, x_hi, x_lo);
        k_split_pack<<<G_N * D_N / 8 / 256, 256, 0, stream>>>(g, g_hi, g_lo);
        k_gemm_argmax<<<2048, 512, 0, stream>>>(x_hi, x_lo, g_hi, g_lo, invn, pk);
        k_counts<<<B_N / 256, 256, 0, stream>>>(pk, counts);
        k_scatter<<<B_N, 256, 0, stream>>>(x, pk, counts, out);
        k_finalize<<<G_N, 256, 0, stream>>>(g, counts, out);
    } else {
        // fallback: fp32 vector path (128 KiB scratch)
        float* invn_f = (float*)ws;
        int* assign_f = (int*)(ws + (size_t)G_N * 4);
        int* counts_f = (int*)(ws + (size_t)(G_N + B_N) * 4);
        hipMemsetAsync(counts_f, 0, (size_t)G_N * sizeof(int), stream);
        k_norms<<<G_N, 256, 0, stream>>>(g, invn_f);
        k_argmax_fp32<<<B_N / 64, 256, 0, stream>>>(x, g, invn_f, assign_f);
        k_counts_i<<<B_N / 256, 256, 0, stream>>>(assign_f, counts_f);
        k_scatter_i<<<B_N, 256, 0, stream>>>(x, assign_f, counts_f, out);
        k_finalize<<<G_N, 256, 0, stream>>>(g, counts_f, out);
    }
}